// Round 1
// baseline (1297.051 us; speedup 1.0000x reference)
//
#include <hip/hip_runtime.h>

#define N_NODES 100000
#define E_EDGES 1600000
#define EP      (E_EDGES + N_NODES)   // edges + self loops = 1,700,000
#define P_CAND  262144
#define IN_C    128
#define HID     64
#define NEG_SLOPE 0.2f

// ---------------- CSR build ----------------

__global__ void deg_kernel(const int* __restrict__ ei, int* __restrict__ deg) {
    int i = blockIdx.x * blockDim.x + threadIdx.x;
    int stride = gridDim.x * blockDim.x;
    for (; i < EP; i += stride) {
        int dst = (i < E_EDGES) ? ei[E_EDGES + i] : (i - E_EDGES);
        atomicAdd(&deg[dst], 1);
    }
}

// single block, 1024 threads: per-thread serial chunk sums -> block scan -> serial writeback
__global__ void scan_kernel(const int* __restrict__ deg, int* __restrict__ off,
                            int* __restrict__ cursor) {
    __shared__ int sums[1024];
    int tid = threadIdx.x;
    const int chunk = (N_NODES + 1023) / 1024;   // 98
    int b = tid * chunk;
    int e = min(b + chunk, N_NODES);
    int s = 0;
    for (int i = b; i < e; i++) s += deg[i];
    sums[tid] = s;
    __syncthreads();
    for (int d = 1; d < 1024; d <<= 1) {
        int t = (tid >= d) ? sums[tid - d] : 0;
        __syncthreads();
        sums[tid] += t;
        __syncthreads();
    }
    int run = sums[tid] - s;   // exclusive prefix
    for (int i = b; i < e; i++) { off[i] = run; cursor[i] = run; run += deg[i]; }
    if (tid == 1023) off[N_NODES] = run;   // = EP (thread 1023's chunk is empty)
}

__global__ void scatter_kernel(const int* __restrict__ ei, int* __restrict__ cursor,
                               int* __restrict__ csr_src) {
    int i = blockIdx.x * blockDim.x + threadIdx.x;
    int stride = gridDim.x * blockDim.x;
    for (; i < EP; i += stride) {
        int src, dst;
        if (i < E_EDGES) { src = ei[i]; dst = ei[E_EDGES + i]; }
        else             { src = i - E_EDGES; dst = src; }
        int pos = atomicAdd(&cursor[dst], 1);
        csr_src[pos] = src;
    }
}

// ---------------- Layer 1: GEMM + attention dots ----------------
// one node per 128-thread block; col = tid; wave w == head w

__global__ __launch_bounds__(128) void gemm1_kernel(
        const float* __restrict__ x, const float* __restrict__ W1,
        const float* __restrict__ att_src1, const float* __restrict__ att_dst1,
        float* __restrict__ xw1, float* __restrict__ as1, float* __restrict__ ad1) {
    int n = blockIdx.x;
    int tid = threadIdx.x;
    __shared__ float xs[IN_C];
    xs[tid] = x[n * IN_C + tid];
    __syncthreads();
    float acc = 0.f;
#pragma unroll 8
    for (int k = 0; k < IN_C; k++) acc = fmaf(xs[k], W1[k * 128 + tid], acc);
    xw1[n * 128 + tid] = acc;
    float ps = acc * att_src1[tid];
    float pd = acc * att_dst1[tid];
    for (int o = 32; o > 0; o >>= 1) {
        ps += __shfl_down(ps, o, 64);
        pd += __shfl_down(pd, o, 64);
    }
    int lane = tid & 63, wv = tid >> 6;
    if (lane == 0) { as1[n * 2 + wv] = ps; ad1[n * 2 + wv] = pd; }
}

// ---------------- Layer 1 aggregation: one wave per node ----------------

__global__ __launch_bounds__(256) void agg1_kernel(
        const int* __restrict__ off, const int* __restrict__ csr_src,
        const float* __restrict__ xw1, const float* __restrict__ as1,
        const float* __restrict__ ad1, const float* __restrict__ b1,
        float* __restrict__ h) {
    int wv = threadIdx.x >> 6, lane = threadIdx.x & 63;
    int n = blockIdx.x * 4 + wv;
    if (n >= N_NODES) return;
    int s = off[n], e = off[n + 1];
    float adn0 = ad1[n * 2], adn1 = ad1[n * 2 + 1];
    float acc0 = 0.f, acc1 = 0.f, sum0 = 0.f, sum1 = 0.f;
    for (int j = s; j < e; j++) {
        int src = csr_src[j];
        float a0 = as1[src * 2], a1 = as1[src * 2 + 1];
        float e0 = a0 + adn0; e0 = e0 > 0.f ? e0 : NEG_SLOPE * e0;
        float e1 = a1 + adn1; e1 = e1 > 0.f ? e1 : NEG_SLOPE * e1;
        float x0 = __expf(e0), x1 = __expf(e1);
        sum0 += x0; sum1 += x1;
        const float* row = xw1 + (long)src * 128;
        acc0 = fmaf(row[lane], x0, acc0);
        acc1 = fmaf(row[64 + lane], x1, acc1);
    }
    float v0 = acc0 / sum0 + b1[lane];
    float v1 = acc1 / sum1 + b1[64 + lane];
    h[n * 128 + lane]      = v0 > 0.f ? v0 : 0.f;   // relu
    h[n * 128 + 64 + lane] = v1 > 0.f ? v1 : 0.f;
}

// ---------------- Layer 2: GEMM (128->64) + attention dots ----------------
// 4 nodes per 256-thread block, one wave per node

__global__ __launch_bounds__(256) void gemm2_kernel(
        const float* __restrict__ h, const float* __restrict__ W2,
        const float* __restrict__ att_src2, const float* __restrict__ att_dst2,
        float* __restrict__ xw2, float* __restrict__ as2, float* __restrict__ ad2) {
    int wv = threadIdx.x >> 6, lane = threadIdx.x & 63;
    int n = blockIdx.x * 4 + wv;
    if (n >= N_NODES) return;
    __shared__ float hs[4][128];
    hs[wv][lane]      = h[n * 128 + lane];
    hs[wv][64 + lane] = h[n * 128 + 64 + lane];
    // wave-local LDS: no cross-wave sharing, compiler inserts lgkmcnt waits
    float acc = 0.f;
#pragma unroll 8
    for (int k = 0; k < 128; k++) acc = fmaf(hs[wv][k], W2[k * 64 + lane], acc);
    xw2[n * 64 + lane] = acc;
    float ps = acc * att_src2[lane], pd = acc * att_dst2[lane];
    for (int o = 32; o > 0; o >>= 1) {
        ps += __shfl_down(ps, o, 64);
        pd += __shfl_down(pd, o, 64);
    }
    if (lane == 0) { as2[n] = ps; ad2[n] = pd; }
}

// ---------------- Layer 2 aggregation ----------------

__global__ __launch_bounds__(256) void agg2_kernel(
        const int* __restrict__ off, const int* __restrict__ csr_src,
        const float* __restrict__ xw2, const float* __restrict__ as2,
        const float* __restrict__ ad2, const float* __restrict__ b2,
        float* __restrict__ z) {
    int wv = threadIdx.x >> 6, lane = threadIdx.x & 63;
    int n = blockIdx.x * 4 + wv;
    if (n >= N_NODES) return;
    int s = off[n], e = off[n + 1];
    float adn = ad2[n];
    float acc = 0.f, sum = 0.f;
    for (int j = s; j < e; j++) {
        int src = csr_src[j];
        float a = as2[src];
        float ev = a + adn; ev = ev > 0.f ? ev : NEG_SLOPE * ev;
        float xv = __expf(ev);
        sum += xv;
        acc = fmaf(xw2[(long)src * 64 + lane], xv, acc);
    }
    z[n * 64 + lane] = acc / sum + b2[lane];
}

// ---------------- Link decode: one wave per candidate edge ----------------

__global__ __launch_bounds__(256) void decode_kernel(
        const int* __restrict__ pos_ei, const int* __restrict__ neg_ei,
        const float* __restrict__ z, const float* __restrict__ lw,
        const float* __restrict__ lb, float* __restrict__ out) {
    int wv = threadIdx.x >> 6, lane = threadIdx.x & 63;
    int idx = blockIdx.x * 4 + wv;
    if (idx >= 2 * P_CAND) return;
    const int* ei; int p;
    if (idx < P_CAND) { ei = pos_ei; p = idx; }
    else              { ei = neg_ei; p = idx - P_CAND; }
    int sN = ei[p], dN = ei[P_CAND + p];
    float v = z[(long)sN * 64 + lane] * lw[lane] + z[(long)dN * 64 + lane] * lw[64 + lane];
    for (int o = 32; o > 0; o >>= 1) v += __shfl_down(v, o, 64);
    if (lane == 0) out[idx] = v + lb[0];
}

// ---------------- launch ----------------

extern "C" void kernel_launch(void* const* d_in, const int* in_sizes, int n_in,
                              void* d_out, int out_size, void* d_ws, size_t ws_size,
                              hipStream_t stream) {
    const float* x        = (const float*)d_in[0];
    const int*   ei       = (const int*)d_in[1];
    // d_in[2] edge_weight: unused by reference
    const int*   pos_ei   = (const int*)d_in[3];
    const int*   neg_ei   = (const int*)d_in[4];
    const float* W1       = (const float*)d_in[5];
    const float* att_src1 = (const float*)d_in[6];
    const float* att_dst1 = (const float*)d_in[7];
    const float* b1       = (const float*)d_in[8];
    const float* W2       = (const float*)d_in[9];
    const float* att_src2 = (const float*)d_in[10];
    const float* att_dst2 = (const float*)d_in[11];
    const float* b2       = (const float*)d_in[12];
    const float* lw       = (const float*)d_in[13];
    const float* lb       = (const float*)d_in[14];
    float* out = (float*)d_out;

    char* ws = (char*)d_ws;
    size_t o = 0;
    auto alloc = [&](size_t bytes) -> char* {
        char* p = ws + o;
        o += (bytes + 255) & ~(size_t)255;
        return p;
    };
    float* xw1    = (float*)alloc((size_t)N_NODES * 128 * 4);  // reused: xw2 | z
    float* h      = (float*)alloc((size_t)N_NODES * 128 * 4);
    float* as1    = (float*)alloc((size_t)N_NODES * 2 * 4);
    float* ad1    = (float*)alloc((size_t)N_NODES * 2 * 4);
    float* as2    = (float*)alloc((size_t)N_NODES * 4);
    float* ad2    = (float*)alloc((size_t)N_NODES * 4);
    int*   deg    = (int*)alloc((size_t)N_NODES * 4);
    int*   off    = (int*)alloc((size_t)(N_NODES + 1) * 4);
    int*   cursor = (int*)alloc((size_t)N_NODES * 4);
    int*   csr    = (int*)alloc((size_t)EP * 4);
    float* xw2 = xw1;                        // first N*64 of the xw1 region
    float* z   = xw1 + (size_t)N_NODES * 64; // second N*64 (disjoint from xw2)

    hipMemsetAsync(deg, 0, (size_t)N_NODES * 4, stream);
    deg_kernel<<<2048, 256, 0, stream>>>(ei, deg);
    scan_kernel<<<1, 1024, 0, stream>>>(deg, off, cursor);
    scatter_kernel<<<2048, 256, 0, stream>>>(ei, cursor, csr);
    gemm1_kernel<<<N_NODES, 128, 0, stream>>>(x, W1, att_src1, att_dst1, xw1, as1, ad1);
    agg1_kernel<<<(N_NODES + 3) / 4, 256, 0, stream>>>(off, csr, xw1, as1, ad1, b1, h);
    gemm2_kernel<<<(N_NODES + 3) / 4, 256, 0, stream>>>(h, W2, att_src2, att_dst2, xw2, as2, ad2);
    agg2_kernel<<<(N_NODES + 3) / 4, 256, 0, stream>>>(off, csr, xw2, as2, ad2, b2, z);
    decode_kernel<<<(2 * P_CAND + 3) / 4, 256, 0, stream>>>(pos_ei, neg_ei, z, lw, lb, out);
}

// Round 2
// 1025.773 us; speedup vs baseline: 1.2645x; 1.2645x over previous
//
#include <hip/hip_runtime.h>

#define N_NODES 100000
#define E_EDGES 1600000
#define EP      (E_EDGES + N_NODES)   // edges + self loops = 1,700,000
#define P_CAND  262144
#define IN_C    128
#define HID     64
#define NEG_SLOPE 0.2f

// ---------------- CSR build ----------------

__global__ void deg_kernel(const int* __restrict__ ei, int* __restrict__ deg) {
    int i = blockIdx.x * blockDim.x + threadIdx.x;
    int stride = gridDim.x * blockDim.x;
    for (; i < EP; i += stride) {
        int dst = (i < E_EDGES) ? ei[E_EDGES + i] : (i - E_EDGES);
        atomicAdd(&deg[dst], 1);
    }
}

// single block, 1024 threads: per-thread serial chunk sums -> block scan -> serial writeback
__global__ void scan_kernel(const int* __restrict__ deg, int* __restrict__ off,
                            int* __restrict__ cursor) {
    __shared__ int sums[1024];
    int tid = threadIdx.x;
    const int chunk = (N_NODES + 1023) / 1024;   // 98
    int b = tid * chunk;
    int e = min(b + chunk, N_NODES);
    int s = 0;
    for (int i = b; i < e; i++) s += deg[i];
    sums[tid] = s;
    __syncthreads();
    for (int d = 1; d < 1024; d <<= 1) {
        int t = (tid >= d) ? sums[tid - d] : 0;
        __syncthreads();
        sums[tid] += t;
        __syncthreads();
    }
    int run = sums[tid] - s;   // exclusive prefix
    for (int i = b; i < e; i++) { off[i] = run; cursor[i] = run; run += deg[i]; }
    if (tid == 1023) off[N_NODES] = run;   // = EP (thread 1023's chunk is empty)
}

// scatter + fused leaky_relu+exp for layer 1 (as1/ad1 must be ready)
__global__ void scatter_exp1_kernel(const int* __restrict__ ei, int* __restrict__ cursor,
                                    const float* __restrict__ as1, const float* __restrict__ ad1,
                                    int* __restrict__ csr_src, int* __restrict__ csr_dst,
                                    float2* __restrict__ csr_f1) {
    int i = blockIdx.x * blockDim.x + threadIdx.x;
    int stride = gridDim.x * blockDim.x;
    for (; i < EP; i += stride) {
        int src, dst;
        if (i < E_EDGES) { src = ei[i]; dst = ei[E_EDGES + i]; }
        else             { src = i - E_EDGES; dst = src; }
        int pos = atomicAdd(&cursor[dst], 1);
        csr_src[pos] = src;
        csr_dst[pos] = dst;
        float2 a = *(const float2*)&as1[2 * src];
        float2 d = *(const float2*)&ad1[2 * dst];
        float e0 = a.x + d.x; e0 = e0 > 0.f ? e0 : NEG_SLOPE * e0;
        float e1 = a.y + d.y; e1 = e1 > 0.f ? e1 : NEG_SLOPE * e1;
        float2 f; f.x = __expf(e0); f.y = __expf(e1);
        csr_f1[pos] = f;
    }
}

// edge-parallel exp for layer 2 (needs as2/ad2 + csr built)
__global__ void exp2_kernel(const int* __restrict__ csr_src, const int* __restrict__ csr_dst,
                            const float* __restrict__ as2, const float* __restrict__ ad2,
                            float* __restrict__ csr_f2) {
    int i = blockIdx.x * blockDim.x + threadIdx.x;
    if (i >= EP) return;
    float e = as2[csr_src[i]] + ad2[csr_dst[i]];
    e = e > 0.f ? e : NEG_SLOPE * e;
    csr_f2[i] = __expf(e);
}

// ---------------- Layer 1 GEMM: 64 nodes/block, 8n x 4c register tile ----------------
// tid -> cg = tid&31 (cols 4cg..4cg+3), ng = tid>>5 (nodes 8ng..8ng+7)

__global__ __launch_bounds__(256) void gemm1_kernel(
        const float* __restrict__ x, const float* __restrict__ W1,
        const float* __restrict__ att_src1, const float* __restrict__ att_dst1,
        float* __restrict__ xw1, float* __restrict__ as1, float* __restrict__ ad1) {
    __shared__ float xt[128 * 66];          // xt[k][node], pad 2 (b64-aligned rows)
    int tid = threadIdx.x;
    int base = blockIdx.x * 64;
    // stage x block transposed: 64 nodes x 128 k
#pragma unroll 4
    for (int it = 0; it < 32; ++it) {
        int e = it * 256 + tid;
        int nn = e >> 7, c = e & 127;
        float v = (base + nn < N_NODES) ? x[(size_t)base * 128 + e] : 0.f;
        xt[c * 66 + nn] = v;
    }
    __syncthreads();
    int cg = tid & 31, ng = tid >> 5;
    float acc[8][4];
#pragma unroll
    for (int i = 0; i < 8; i++)
#pragma unroll
        for (int j = 0; j < 4; j++) acc[i][j] = 0.f;

#pragma unroll 4
    for (int k = 0; k < 128; ++k) {
        float4 w = *(const float4*)&W1[k * 128 + 4 * cg];
        const float* xr = &xt[k * 66 + 8 * ng];
        float2 a0 = *(const float2*)&xr[0];
        float2 a1 = *(const float2*)&xr[2];
        float2 a2 = *(const float2*)&xr[4];
        float2 a3 = *(const float2*)&xr[6];
        float xv[8] = {a0.x, a0.y, a1.x, a1.y, a2.x, a2.y, a3.x, a3.y};
#pragma unroll
        for (int i = 0; i < 8; i++) {
            acc[i][0] = fmaf(xv[i], w.x, acc[i][0]);
            acc[i][1] = fmaf(xv[i], w.y, acc[i][1]);
            acc[i][2] = fmaf(xv[i], w.z, acc[i][2]);
            acc[i][3] = fmaf(xv[i], w.w, acc[i][3]);
        }
    }
    // epilogue: write xw1 + attention dots
    int c0 = 4 * cg;
    float s0 = att_src1[c0], s1 = att_src1[c0 + 1], s2 = att_src1[c0 + 2], s3 = att_src1[c0 + 3];
    float d0 = att_dst1[c0], d1 = att_dst1[c0 + 1], d2 = att_dst1[c0 + 2], d3 = att_dst1[c0 + 3];
#pragma unroll
    for (int i = 0; i < 8; i++) {
        int n = base + 8 * ng + i;
        bool ok = n < N_NODES;
        if (ok) *(float4*)&xw1[(size_t)n * 128 + c0] =
            make_float4(acc[i][0], acc[i][1], acc[i][2], acc[i][3]);
        float ps = acc[i][0] * s0 + acc[i][1] * s1 + acc[i][2] * s2 + acc[i][3] * s3;
        float pd = acc[i][0] * d0 + acc[i][1] * d1 + acc[i][2] * d2 + acc[i][3] * d3;
        // reduce over 16-lane groups (cg 0..15 = head0, cg 16..31 = head1)
#pragma unroll
        for (int m = 8; m >= 1; m >>= 1) {
            ps += __shfl_xor(ps, m);
            pd += __shfl_xor(pd, m);
        }
        if (ok && (cg == 0 || cg == 16)) {
            int h = cg >> 4;
            as1[n * 2 + h] = ps;
            ad1[n * 2 + h] = pd;
        }
    }
}

// ---------------- Layer 1 aggregation: one wave per node ----------------
// lane l holds cols 2l,2l+1 (lanes 0-31 head0, 32-63 head1)

__global__ __launch_bounds__(256) void agg1_kernel(
        const int* __restrict__ off, const int* __restrict__ csr_src,
        const float2* __restrict__ csr_f1, const float* __restrict__ xw1,
        const float* __restrict__ b1, float* __restrict__ h) {
    int wv = threadIdx.x >> 6, lane = threadIdx.x & 63;
    int n = blockIdx.x * 4 + wv;
    if (n >= N_NODES) return;
    int s = off[n], e = off[n + 1];
    float acc0 = 0.f, acc1 = 0.f, sum0 = 0.f, sum1 = 0.f;
    for (int b = s; b < e; b += 64) {
        int cnt = min(64, e - b);
        int l = lane < cnt ? lane : cnt - 1;
        int srcv = csr_src[b + l];
        float2 fv = (lane < cnt) ? csr_f1[b + l] : make_float2(0.f, 0.f);
        float r0 = fv.x, r1 = fv.y;
#pragma unroll
        for (int m = 32; m >= 1; m >>= 1) { r0 += __shfl_xor(r0, m); r1 += __shfl_xor(r1, m); }
        sum0 += r0; sum1 += r1;
        for (int jj = 0; jj < cnt; jj++) {
            int src = __shfl(srcv, jj);
            float f0 = __shfl(fv.x, jj);
            float f1 = __shfl(fv.y, jj);
            float f = (lane < 32) ? f0 : f1;
            float2 row = *(const float2*)&xw1[(size_t)src * 128 + 2 * lane];
            acc0 = fmaf(row.x, f, acc0);
            acc1 = fmaf(row.y, f, acc1);
        }
    }
    float sum = (lane < 32) ? sum0 : sum1;
    int c = 2 * lane;
    float v0 = acc0 / sum + b1[c];
    float v1 = acc1 / sum + b1[c + 1];
    float2 o; o.x = v0 > 0.f ? v0 : 0.f; o.y = v1 > 0.f ? v1 : 0.f;
    *(float2*)&h[(size_t)n * 128 + c] = o;
}

// ---------------- Layer 2 GEMM: 64 nodes/block, 4n x 4c tile ----------------
// tid -> cg = tid&15 (cols 4cg..), ng = tid>>4 (nodes 4ng..4ng+3)

__global__ __launch_bounds__(256) void gemm2_kernel(
        const float* __restrict__ h, const float* __restrict__ W2,
        const float* __restrict__ att_src2, const float* __restrict__ att_dst2,
        float* __restrict__ xw2, float* __restrict__ as2, float* __restrict__ ad2) {
    __shared__ float xt[128 * 66];
    int tid = threadIdx.x;
    int base = blockIdx.x * 64;
#pragma unroll 4
    for (int it = 0; it < 32; ++it) {
        int e = it * 256 + tid;
        int nn = e >> 7, c = e & 127;
        float v = (base + nn < N_NODES) ? h[(size_t)base * 128 + e] : 0.f;
        xt[c * 66 + nn] = v;
    }
    __syncthreads();
    int cg = tid & 15, ng = tid >> 4;
    float acc[4][4];
#pragma unroll
    for (int i = 0; i < 4; i++)
#pragma unroll
        for (int j = 0; j < 4; j++) acc[i][j] = 0.f;

#pragma unroll 4
    for (int k = 0; k < 128; ++k) {
        float4 w = *(const float4*)&W2[k * 64 + 4 * cg];
        const float* xr = &xt[k * 66 + 4 * ng];
        float2 a0 = *(const float2*)&xr[0];
        float2 a1 = *(const float2*)&xr[2];
        float xv[4] = {a0.x, a0.y, a1.x, a1.y};
#pragma unroll
        for (int i = 0; i < 4; i++) {
            acc[i][0] = fmaf(xv[i], w.x, acc[i][0]);
            acc[i][1] = fmaf(xv[i], w.y, acc[i][1]);
            acc[i][2] = fmaf(xv[i], w.z, acc[i][2]);
            acc[i][3] = fmaf(xv[i], w.w, acc[i][3]);
        }
    }
    int c0 = 4 * cg;
    float s0 = att_src2[c0], s1 = att_src2[c0 + 1], s2 = att_src2[c0 + 2], s3 = att_src2[c0 + 3];
    float d0 = att_dst2[c0], d1 = att_dst2[c0 + 1], d2 = att_dst2[c0 + 2], d3 = att_dst2[c0 + 3];
#pragma unroll
    for (int i = 0; i < 4; i++) {
        int n = base + 4 * ng + i;
        bool ok = n < N_NODES;
        if (ok) *(float4*)&xw2[(size_t)n * 64 + c0] =
            make_float4(acc[i][0], acc[i][1], acc[i][2], acc[i][3]);
        float ps = acc[i][0] * s0 + acc[i][1] * s1 + acc[i][2] * s2 + acc[i][3] * s3;
        float pd = acc[i][0] * d0 + acc[i][1] * d1 + acc[i][2] * d2 + acc[i][3] * d3;
#pragma unroll
        for (int m = 8; m >= 1; m >>= 1) {
            ps += __shfl_xor(ps, m);
            pd += __shfl_xor(pd, m);
        }
        if (ok && cg == 0) { as2[n] = ps; ad2[n] = pd; }
    }
}

// ---------------- Layer 2 aggregation: one wave per node, col = lane ----------------

__global__ __launch_bounds__(256) void agg2_kernel(
        const int* __restrict__ off, const int* __restrict__ csr_src,
        const float* __restrict__ csr_f2, const float* __restrict__ xw2,
        const float* __restrict__ b2, float* __restrict__ z) {
    int wv = threadIdx.x >> 6, lane = threadIdx.x & 63;
    int n = blockIdx.x * 4 + wv;
    if (n >= N_NODES) return;
    int s = off[n], e = off[n + 1];
    float acc = 0.f, sum = 0.f;
    for (int b = s; b < e; b += 64) {
        int cnt = min(64, e - b);
        int l = lane < cnt ? lane : cnt - 1;
        int srcv = csr_src[b + l];
        float fv = (lane < cnt) ? csr_f2[b + l] : 0.f;
        float r = fv;
#pragma unroll
        for (int m = 32; m >= 1; m >>= 1) r += __shfl_xor(r, m);
        sum += r;
        for (int jj = 0; jj < cnt; jj++) {
            int src = __shfl(srcv, jj);
            float f = __shfl(fv, jj);
            acc = fmaf(xw2[(size_t)src * 64 + lane], f, acc);
        }
    }
    z[(size_t)n * 64 + lane] = acc / sum + b2[lane];
}

// ---------------- Link decode: one wave per candidate, split-wave float2 ----------------

__global__ __launch_bounds__(256) void decode_kernel(
        const int* __restrict__ pos_ei, const int* __restrict__ neg_ei,
        const float* __restrict__ z, const float* __restrict__ lw,
        const float* __restrict__ lb, float* __restrict__ out) {
    int wv = threadIdx.x >> 6, lane = threadIdx.x & 63;
    int idx = blockIdx.x * 4 + wv;
    if (idx >= 2 * P_CAND) return;
    const int* ei; int p;
    if (idx < P_CAND) { ei = pos_ei; p = idx; }
    else              { ei = neg_ei; p = idx - P_CAND; }
    int sN = ei[p], dN = ei[P_CAND + p];
    float2 zz, ww;
    if (lane < 32) {
        zz = *(const float2*)&z[(size_t)sN * 64 + 2 * lane];
        ww = *(const float2*)&lw[2 * lane];
    } else {
        int q = lane - 32;
        zz = *(const float2*)&z[(size_t)dN * 64 + 2 * q];
        ww = *(const float2*)&lw[64 + 2 * q];
    }
    float v = zz.x * ww.x + zz.y * ww.y;
#pragma unroll
    for (int m = 32; m >= 1; m >>= 1) v += __shfl_xor(v, m);
    if (lane == 0) out[idx] = v + lb[0];
}

// ---------------- launch ----------------

extern "C" void kernel_launch(void* const* d_in, const int* in_sizes, int n_in,
                              void* d_out, int out_size, void* d_ws, size_t ws_size,
                              hipStream_t stream) {
    const float* x        = (const float*)d_in[0];
    const int*   ei       = (const int*)d_in[1];
    const int*   pos_ei   = (const int*)d_in[3];
    const int*   neg_ei   = (const int*)d_in[4];
    const float* W1       = (const float*)d_in[5];
    const float* att_src1 = (const float*)d_in[6];
    const float* att_dst1 = (const float*)d_in[7];
    const float* b1       = (const float*)d_in[8];
    const float* W2       = (const float*)d_in[9];
    const float* att_src2 = (const float*)d_in[10];
    const float* att_dst2 = (const float*)d_in[11];
    const float* b2       = (const float*)d_in[12];
    const float* lw       = (const float*)d_in[13];
    const float* lb       = (const float*)d_in[14];
    float* out = (float*)d_out;

    char* ws = (char*)d_ws;
    size_t o = 0;
    auto alloc = [&](size_t bytes) -> char* {
        char* p = ws + o;
        o += (bytes + 511) & ~(size_t)511;
        return p;
    };
    float*  xw1    = (float*)alloc((size_t)N_NODES * 128 * 4);  // reused: xw2 | z
    float*  h      = (float*)alloc((size_t)N_NODES * 128 * 4);
    float*  as1    = (float*)alloc((size_t)N_NODES * 2 * 4);
    float*  ad1    = (float*)alloc((size_t)N_NODES * 2 * 4);
    float*  as2    = (float*)alloc((size_t)N_NODES * 4);
    float*  ad2    = (float*)alloc((size_t)N_NODES * 4);
    int*    deg    = (int*)alloc((size_t)N_NODES * 4);
    int*    off    = (int*)alloc((size_t)(N_NODES + 1) * 4);
    int*    cursor = (int*)alloc((size_t)N_NODES * 4);
    int*    csr    = (int*)alloc((size_t)EP * 4);
    int*    csrd   = (int*)alloc((size_t)EP * 4);
    float2* csr_f1 = (float2*)alloc((size_t)EP * 8);
    float*  xw2 = xw1;                         // first N*64 of xw1 region
    float*  z   = xw1 + (size_t)N_NODES * 64;  // second N*64
    float*  csr_f2 = (float*)csr_f1;           // csr_f1 dead after agg1

    hipMemsetAsync(deg, 0, (size_t)N_NODES * 4, stream);
    deg_kernel<<<2048, 256, 0, stream>>>(ei, deg);
    scan_kernel<<<1, 1024, 0, stream>>>(deg, off, cursor);
    gemm1_kernel<<<(N_NODES + 63) / 64, 256, 0, stream>>>(x, W1, att_src1, att_dst1, xw1, as1, ad1);
    scatter_exp1_kernel<<<2048, 256, 0, stream>>>(ei, cursor, as1, ad1, csr, csrd, csr_f1);
    agg1_kernel<<<(N_NODES + 3) / 4, 256, 0, stream>>>(off, csr, csr_f1, xw1, b1, h);
    gemm2_kernel<<<(N_NODES + 63) / 64, 256, 0, stream>>>(h, W2, att_src2, att_dst2, xw2, as2, ad2);
    exp2_kernel<<<(EP + 255) / 256, 256, 0, stream>>>(csr, csrd, as2, ad2, csr_f2);
    agg2_kernel<<<(N_NODES + 3) / 4, 256, 0, stream>>>(off, csr, csr_f2, xw2, b2, z);
    decode_kernel<<<(2 * P_CAND + 3) / 4, 256, 0, stream>>>(pos_ei, neg_ei, z, lw, lb, out);
}

// Round 3
// 826.299 us; speedup vs baseline: 1.5697x; 1.2414x over previous
//
#include <hip/hip_runtime.h>

#define N_NODES 100000
#define E_EDGES 1600000
#define EP      (E_EDGES + N_NODES)   // edges + self loops = 1,700,000
#define P_CAND  262144
#define IN_C    128
#define HID     64
#define NEG_SLOPE 0.2f

#define SCAN_NB ((N_NODES + 255) / 256)   // 391 blocks

// ---------------- CSR build ----------------

__global__ void deg_kernel(const int* __restrict__ ei, int* __restrict__ deg) {
    int i = blockIdx.x * blockDim.x + threadIdx.x;
    int stride = gridDim.x * blockDim.x;
    for (; i < EP; i += stride) {
        int dst = (i < E_EDGES) ? ei[E_EDGES + i] : (i - E_EDGES);
        atomicAdd(&deg[dst], 1);
    }
}

// phase 1: per-block sums (256 nodes per block)
__global__ __launch_bounds__(256) void partial_kernel(const int* __restrict__ deg,
                                                      int* __restrict__ bsum) {
    int t = threadIdx.x, b = blockIdx.x;
    int i = b * 256 + t;
    int v = (i < N_NODES) ? deg[i] : 0;
    __shared__ int ws[4];
#pragma unroll
    for (int m = 32; m >= 1; m >>= 1) v += __shfl_xor(v, m);
    if ((t & 63) == 0) ws[t >> 6] = v;
    __syncthreads();
    if (t == 0) bsum[b] = ws[0] + ws[1] + ws[2] + ws[3];
}

// phase 2: single small block scans the 391 block sums (exclusive)
__global__ __launch_bounds__(512) void scanb_kernel(const int* __restrict__ bsum,
                                                    int* __restrict__ bbase) {
    __shared__ int s[512];
    int t = threadIdx.x;
    int v = (t < SCAN_NB) ? bsum[t] : 0;
    s[t] = v;
    __syncthreads();
    for (int d = 1; d < 512; d <<= 1) {
        int x = (t >= d) ? s[t - d] : 0;
        __syncthreads();
        s[t] += x;
        __syncthreads();
    }
    if (t < SCAN_NB) bbase[t] = s[t] - v;
}

// phase 3: per-block exclusive scan + base -> off/cursor
__global__ __launch_bounds__(256) void offs_kernel(const int* __restrict__ deg,
                                                   const int* __restrict__ bbase,
                                                   int* __restrict__ off,
                                                   int* __restrict__ cursor) {
    __shared__ int s[256];
    int t = threadIdx.x, b = blockIdx.x;
    int i = b * 256 + t;
    int v = (i < N_NODES) ? deg[i] : 0;
    s[t] = v;
    __syncthreads();
    for (int d = 1; d < 256; d <<= 1) {
        int x = (t >= d) ? s[t - d] : 0;
        __syncthreads();
        s[t] += x;
        __syncthreads();
    }
    int ex = s[t] - v + bbase[b];
    if (i < N_NODES) { off[i] = ex; cursor[i] = ex; }
    if (i == N_NODES - 1) off[N_NODES] = ex + v;
}

// scatter + fused leaky_relu+exp for layer 1 (as1/ad1 must be ready)
__global__ void scatter_exp1_kernel(const int* __restrict__ ei, int* __restrict__ cursor,
                                    const float* __restrict__ as1, const float* __restrict__ ad1,
                                    int* __restrict__ csr_src, int* __restrict__ csr_dst,
                                    float2* __restrict__ csr_f1) {
    int i = blockIdx.x * blockDim.x + threadIdx.x;
    int stride = gridDim.x * blockDim.x;
    for (; i < EP; i += stride) {
        int src, dst;
        if (i < E_EDGES) { src = ei[i]; dst = ei[E_EDGES + i]; }
        else             { src = i - E_EDGES; dst = src; }
        int pos = atomicAdd(&cursor[dst], 1);
        csr_src[pos] = src;
        csr_dst[pos] = dst;
        float2 a = *(const float2*)&as1[2 * src];
        float2 d = *(const float2*)&ad1[2 * dst];
        float e0 = a.x + d.x; e0 = e0 > 0.f ? e0 : NEG_SLOPE * e0;
        float e1 = a.y + d.y; e1 = e1 > 0.f ? e1 : NEG_SLOPE * e1;
        float2 f; f.x = __expf(e0); f.y = __expf(e1);
        csr_f1[pos] = f;
    }
}

// edge-parallel exp for layer 2 (needs as2/ad2 + csr built)
__global__ void exp2_kernel(const int* __restrict__ csr_src, const int* __restrict__ csr_dst,
                            const float* __restrict__ as2, const float* __restrict__ ad2,
                            float* __restrict__ csr_f2) {
    int i = blockIdx.x * blockDim.x + threadIdx.x;
    if (i >= EP) return;
    float e = as2[csr_src[i]] + ad2[csr_dst[i]];
    e = e > 0.f ? e : NEG_SLOPE * e;
    csr_f2[i] = __expf(e);
}

// ---------------- Layer 1 GEMM: 64 nodes/block, 8n x 4c register tile ----------------

__global__ __launch_bounds__(256) void gemm1_kernel(
        const float* __restrict__ x, const float* __restrict__ W1,
        const float* __restrict__ att_src1, const float* __restrict__ att_dst1,
        float* __restrict__ xw1, float* __restrict__ as1, float* __restrict__ ad1) {
    __shared__ float xt[128 * 66];          // xt[k][node], pad 2
    int tid = threadIdx.x;
    int base = blockIdx.x * 64;
#pragma unroll 4
    for (int it = 0; it < 32; ++it) {
        int e = it * 256 + tid;
        int nn = e >> 7, c = e & 127;
        float v = (base + nn < N_NODES) ? x[(size_t)base * 128 + e] : 0.f;
        xt[c * 66 + nn] = v;
    }
    __syncthreads();
    int cg = tid & 31, ng = tid >> 5;
    float acc[8][4];
#pragma unroll
    for (int i = 0; i < 8; i++)
#pragma unroll
        for (int j = 0; j < 4; j++) acc[i][j] = 0.f;

#pragma unroll 4
    for (int k = 0; k < 128; ++k) {
        float4 w = *(const float4*)&W1[k * 128 + 4 * cg];
        const float* xr = &xt[k * 66 + 8 * ng];
        float2 a0 = *(const float2*)&xr[0];
        float2 a1 = *(const float2*)&xr[2];
        float2 a2 = *(const float2*)&xr[4];
        float2 a3 = *(const float2*)&xr[6];
        float xv[8] = {a0.x, a0.y, a1.x, a1.y, a2.x, a2.y, a3.x, a3.y};
#pragma unroll
        for (int i = 0; i < 8; i++) {
            acc[i][0] = fmaf(xv[i], w.x, acc[i][0]);
            acc[i][1] = fmaf(xv[i], w.y, acc[i][1]);
            acc[i][2] = fmaf(xv[i], w.z, acc[i][2]);
            acc[i][3] = fmaf(xv[i], w.w, acc[i][3]);
        }
    }
    int c0 = 4 * cg;
    float s0 = att_src1[c0], s1 = att_src1[c0 + 1], s2 = att_src1[c0 + 2], s3 = att_src1[c0 + 3];
    float d0 = att_dst1[c0], d1 = att_dst1[c0 + 1], d2 = att_dst1[c0 + 2], d3 = att_dst1[c0 + 3];
#pragma unroll
    for (int i = 0; i < 8; i++) {
        int n = base + 8 * ng + i;
        bool ok = n < N_NODES;
        if (ok) *(float4*)&xw1[(size_t)n * 128 + c0] =
            make_float4(acc[i][0], acc[i][1], acc[i][2], acc[i][3]);
        float ps = acc[i][0] * s0 + acc[i][1] * s1 + acc[i][2] * s2 + acc[i][3] * s3;
        float pd = acc[i][0] * d0 + acc[i][1] * d1 + acc[i][2] * d2 + acc[i][3] * d3;
#pragma unroll
        for (int m = 8; m >= 1; m >>= 1) {
            ps += __shfl_xor(ps, m);
            pd += __shfl_xor(pd, m);
        }
        if (ok && (cg == 0 || cg == 16)) {
            int h = cg >> 4;
            as1[n * 2 + h] = ps;
            ad1[n * 2 + h] = pd;
        }
    }
}

// ---------------- Layer 1 aggregation: one wave per node ----------------

__global__ __launch_bounds__(256) void agg1_kernel(
        const int* __restrict__ off, const int* __restrict__ csr_src,
        const float2* __restrict__ csr_f1, const float* __restrict__ xw1,
        const float* __restrict__ b1, float* __restrict__ h) {
    int wv = threadIdx.x >> 6, lane = threadIdx.x & 63;
    int n = blockIdx.x * 4 + wv;
    if (n >= N_NODES) return;
    int s = off[n], e = off[n + 1];
    float acc0 = 0.f, acc1 = 0.f, sum0 = 0.f, sum1 = 0.f;
    for (int b = s; b < e; b += 64) {
        int cnt = min(64, e - b);
        int l = lane < cnt ? lane : cnt - 1;
        int srcv = csr_src[b + l];
        float2 fv = (lane < cnt) ? csr_f1[b + l] : make_float2(0.f, 0.f);
        float r0 = fv.x, r1 = fv.y;
#pragma unroll
        for (int m = 32; m >= 1; m >>= 1) { r0 += __shfl_xor(r0, m); r1 += __shfl_xor(r1, m); }
        sum0 += r0; sum1 += r1;
        for (int jj = 0; jj < cnt; jj++) {
            int src = __shfl(srcv, jj);
            float f0 = __shfl(fv.x, jj);
            float f1 = __shfl(fv.y, jj);
            float f = (lane < 32) ? f0 : f1;
            float2 row = *(const float2*)&xw1[(size_t)src * 128 + 2 * lane];
            acc0 = fmaf(row.x, f, acc0);
            acc1 = fmaf(row.y, f, acc1);
        }
    }
    float sum = (lane < 32) ? sum0 : sum1;
    int c = 2 * lane;
    float v0 = acc0 / sum + b1[c];
    float v1 = acc1 / sum + b1[c + 1];
    float2 o; o.x = v0 > 0.f ? v0 : 0.f; o.y = v1 > 0.f ? v1 : 0.f;
    *(float2*)&h[(size_t)n * 128 + c] = o;
}

// ---------------- Layer 2 GEMM: 64 nodes/block, 4n x 4c tile ----------------

__global__ __launch_bounds__(256) void gemm2_kernel(
        const float* __restrict__ h, const float* __restrict__ W2,
        const float* __restrict__ att_src2, const float* __restrict__ att_dst2,
        float* __restrict__ xw2, float* __restrict__ as2, float* __restrict__ ad2) {
    __shared__ float xt[128 * 66];
    int tid = threadIdx.x;
    int base = blockIdx.x * 64;
#pragma unroll 4
    for (int it = 0; it < 32; ++it) {
        int e = it * 256 + tid;
        int nn = e >> 7, c = e & 127;
        float v = (base + nn < N_NODES) ? h[(size_t)base * 128 + e] : 0.f;
        xt[c * 66 + nn] = v;
    }
    __syncthreads();
    int cg = tid & 15, ng = tid >> 4;
    float acc[4][4];
#pragma unroll
    for (int i = 0; i < 4; i++)
#pragma unroll
        for (int j = 0; j < 4; j++) acc[i][j] = 0.f;

#pragma unroll 4
    for (int k = 0; k < 128; ++k) {
        float4 w = *(const float4*)&W2[k * 64 + 4 * cg];
        const float* xr = &xt[k * 66 + 4 * ng];
        float2 a0 = *(const float2*)&xr[0];
        float2 a1 = *(const float2*)&xr[2];
        float xv[4] = {a0.x, a0.y, a1.x, a1.y};
#pragma unroll
        for (int i = 0; i < 4; i++) {
            acc[i][0] = fmaf(xv[i], w.x, acc[i][0]);
            acc[i][1] = fmaf(xv[i], w.y, acc[i][1]);
            acc[i][2] = fmaf(xv[i], w.z, acc[i][2]);
            acc[i][3] = fmaf(xv[i], w.w, acc[i][3]);
        }
    }
    int c0 = 4 * cg;
    float s0 = att_src2[c0], s1 = att_src2[c0 + 1], s2 = att_src2[c0 + 2], s3 = att_src2[c0 + 3];
    float d0 = att_dst2[c0], d1 = att_dst2[c0 + 1], d2 = att_dst2[c0 + 2], d3 = att_dst2[c0 + 3];
#pragma unroll
    for (int i = 0; i < 4; i++) {
        int n = base + 4 * ng + i;
        bool ok = n < N_NODES;
        if (ok) *(float4*)&xw2[(size_t)n * 64 + c0] =
            make_float4(acc[i][0], acc[i][1], acc[i][2], acc[i][3]);
        float ps = acc[i][0] * s0 + acc[i][1] * s1 + acc[i][2] * s2 + acc[i][3] * s3;
        float pd = acc[i][0] * d0 + acc[i][1] * d1 + acc[i][2] * d2 + acc[i][3] * d3;
#pragma unroll
        for (int m = 8; m >= 1; m >>= 1) {
            ps += __shfl_xor(ps, m);
            pd += __shfl_xor(pd, m);
        }
        if (ok && cg == 0) { as2[n] = ps; ad2[n] = pd; }
    }
}

// ---------------- Layer 2 aggregation ----------------

__global__ __launch_bounds__(256) void agg2_kernel(
        const int* __restrict__ off, const int* __restrict__ csr_src,
        const float* __restrict__ csr_f2, const float* __restrict__ xw2,
        const float* __restrict__ b2, float* __restrict__ z) {
    int wv = threadIdx.x >> 6, lane = threadIdx.x & 63;
    int n = blockIdx.x * 4 + wv;
    if (n >= N_NODES) return;
    int s = off[n], e = off[n + 1];
    float acc = 0.f, sum = 0.f;
    for (int b = s; b < e; b += 64) {
        int cnt = min(64, e - b);
        int l = lane < cnt ? lane : cnt - 1;
        int srcv = csr_src[b + l];
        float fv = (lane < cnt) ? csr_f2[b + l] : 0.f;
        float r = fv;
#pragma unroll
        for (int m = 32; m >= 1; m >>= 1) r += __shfl_xor(r, m);
        sum += r;
        for (int jj = 0; jj < cnt; jj++) {
            int src = __shfl(srcv, jj);
            float f = __shfl(fv, jj);
            acc = fmaf(xw2[(size_t)src * 64 + lane], f, acc);
        }
    }
    z[(size_t)n * 64 + lane] = acc / sum + b2[lane];
}

// ---------------- Link decode ----------------

__global__ __launch_bounds__(256) void decode_kernel(
        const int* __restrict__ pos_ei, const int* __restrict__ neg_ei,
        const float* __restrict__ z, const float* __restrict__ lw,
        const float* __restrict__ lb, float* __restrict__ out) {
    int wv = threadIdx.x >> 6, lane = threadIdx.x & 63;
    int idx = blockIdx.x * 4 + wv;
    if (idx >= 2 * P_CAND) return;
    const int* ei; int p;
    if (idx < P_CAND) { ei = pos_ei; p = idx; }
    else              { ei = neg_ei; p = idx - P_CAND; }
    int sN = ei[p], dN = ei[P_CAND + p];
    float2 zz, ww;
    if (lane < 32) {
        zz = *(const float2*)&z[(size_t)sN * 64 + 2 * lane];
        ww = *(const float2*)&lw[2 * lane];
    } else {
        int q = lane - 32;
        zz = *(const float2*)&z[(size_t)dN * 64 + 2 * q];
        ww = *(const float2*)&lw[64 + 2 * q];
    }
    float v = zz.x * ww.x + zz.y * ww.y;
#pragma unroll
    for (int m = 32; m >= 1; m >>= 1) v += __shfl_xor(v, m);
    if (lane == 0) out[idx] = v + lb[0];
}

// ---------------- launch ----------------

extern "C" void kernel_launch(void* const* d_in, const int* in_sizes, int n_in,
                              void* d_out, int out_size, void* d_ws, size_t ws_size,
                              hipStream_t stream) {
    const float* x        = (const float*)d_in[0];
    const int*   ei       = (const int*)d_in[1];
    const int*   pos_ei   = (const int*)d_in[3];
    const int*   neg_ei   = (const int*)d_in[4];
    const float* W1       = (const float*)d_in[5];
    const float* att_src1 = (const float*)d_in[6];
    const float* att_dst1 = (const float*)d_in[7];
    const float* b1       = (const float*)d_in[8];
    const float* W2       = (const float*)d_in[9];
    const float* att_src2 = (const float*)d_in[10];
    const float* att_dst2 = (const float*)d_in[11];
    const float* b2       = (const float*)d_in[12];
    const float* lw       = (const float*)d_in[13];
    const float* lb       = (const float*)d_in[14];
    float* out = (float*)d_out;

    char* ws = (char*)d_ws;
    size_t o = 0;
    auto alloc = [&](size_t bytes) -> char* {
        char* p = ws + o;
        o += (bytes + 511) & ~(size_t)511;
        return p;
    };
    float*  xw1    = (float*)alloc((size_t)N_NODES * 128 * 4);  // reused: xw2 | z
    float*  h      = (float*)alloc((size_t)N_NODES * 128 * 4);
    float*  as1    = (float*)alloc((size_t)N_NODES * 2 * 4);
    float*  ad1    = (float*)alloc((size_t)N_NODES * 2 * 4);
    float*  as2    = (float*)alloc((size_t)N_NODES * 4);
    float*  ad2    = (float*)alloc((size_t)N_NODES * 4);
    int*    deg    = (int*)alloc((size_t)N_NODES * 4);
    int*    off    = (int*)alloc((size_t)(N_NODES + 1) * 4);
    int*    cursor = (int*)alloc((size_t)N_NODES * 4);
    int*    bsum   = (int*)alloc((size_t)SCAN_NB * 4);
    int*    bbase  = (int*)alloc((size_t)SCAN_NB * 4);
    int*    csr    = (int*)alloc((size_t)EP * 4);
    int*    csrd   = (int*)alloc((size_t)EP * 4);
    float2* csr_f1 = (float2*)alloc((size_t)EP * 8);
    float*  xw2 = xw1;
    float*  z   = xw1 + (size_t)N_NODES * 64;
    float*  csr_f2 = (float*)csr_f1;

    hipMemsetAsync(deg, 0, (size_t)N_NODES * 4, stream);
    deg_kernel<<<2048, 256, 0, stream>>>(ei, deg);
    partial_kernel<<<SCAN_NB, 256, 0, stream>>>(deg, bsum);
    scanb_kernel<<<1, 512, 0, stream>>>(bsum, bbase);
    offs_kernel<<<SCAN_NB, 256, 0, stream>>>(deg, bbase, off, cursor);
    gemm1_kernel<<<(N_NODES + 63) / 64, 256, 0, stream>>>(x, W1, att_src1, att_dst1, xw1, as1, ad1);
    scatter_exp1_kernel<<<2048, 256, 0, stream>>>(ei, cursor, as1, ad1, csr, csrd, csr_f1);
    agg1_kernel<<<(N_NODES + 3) / 4, 256, 0, stream>>>(off, csr, csr_f1, xw1, b1, h);
    gemm2_kernel<<<(N_NODES + 63) / 64, 256, 0, stream>>>(h, W2, att_src2, att_dst2, xw2, as2, ad2);
    exp2_kernel<<<(EP + 255) / 256, 256, 0, stream>>>(csr, csrd, as2, ad2, csr_f2);
    agg2_kernel<<<(N_NODES + 3) / 4, 256, 0, stream>>>(off, csr, csr_f2, xw2, b2, z);
    decode_kernel<<<(2 * P_CAND + 3) / 4, 256, 0, stream>>>(pos_ei, neg_ei, z, lw, lb, out);
}

// Round 4
// 811.234 us; speedup vs baseline: 1.5989x; 1.0186x over previous
//
#include <hip/hip_runtime.h>

#define N_NODES 100000
#define E_EDGES 1600000
#define EP      (E_EDGES + N_NODES)   // edges + self loops = 1,700,000
#define P_CAND  262144
#define IN_C    128
#define HID     64
#define NEG_SLOPE 0.2f

#define SCAN_NB ((N_NODES + 255) / 256)   // 391 blocks

// ---------------- CSR build ----------------

__global__ void deg_kernel(const int* __restrict__ ei, int* __restrict__ deg) {
    int i = blockIdx.x * blockDim.x + threadIdx.x;
    int stride = gridDim.x * blockDim.x;
    for (; i < EP; i += stride) {
        int dst = (i < E_EDGES) ? ei[E_EDGES + i] : (i - E_EDGES);
        atomicAdd(&deg[dst], 1);
    }
}

// phase 1: per-block sums (256 nodes per block)
__global__ __launch_bounds__(256) void partial_kernel(const int* __restrict__ deg,
                                                      int* __restrict__ bsum) {
    int t = threadIdx.x, b = blockIdx.x;
    int i = b * 256 + t;
    int v = (i < N_NODES) ? deg[i] : 0;
    __shared__ int ws[4];
#pragma unroll
    for (int m = 32; m >= 1; m >>= 1) v += __shfl_xor(v, m);
    if ((t & 63) == 0) ws[t >> 6] = v;
    __syncthreads();
    if (t == 0) bsum[b] = ws[0] + ws[1] + ws[2] + ws[3];
}

// phase 2: single small block scans the 391 block sums (exclusive)
__global__ __launch_bounds__(512) void scanb_kernel(const int* __restrict__ bsum,
                                                    int* __restrict__ bbase) {
    __shared__ int s[512];
    int t = threadIdx.x;
    int v = (t < SCAN_NB) ? bsum[t] : 0;
    s[t] = v;
    __syncthreads();
    for (int d = 1; d < 512; d <<= 1) {
        int x = (t >= d) ? s[t - d] : 0;
        __syncthreads();
        s[t] += x;
        __syncthreads();
    }
    if (t < SCAN_NB) bbase[t] = s[t] - v;
}

// phase 3: per-block exclusive scan + base -> off/cursor
__global__ __launch_bounds__(256) void offs_kernel(const int* __restrict__ deg,
                                                   const int* __restrict__ bbase,
                                                   int* __restrict__ off,
                                                   int* __restrict__ cursor) {
    __shared__ int s[256];
    int t = threadIdx.x, b = blockIdx.x;
    int i = b * 256 + t;
    int v = (i < N_NODES) ? deg[i] : 0;
    s[t] = v;
    __syncthreads();
    for (int d = 1; d < 256; d <<= 1) {
        int x = (t >= d) ? s[t - d] : 0;
        __syncthreads();
        s[t] += x;
        __syncthreads();
    }
    int ex = s[t] - v + bbase[b];
    if (i < N_NODES) { off[i] = ex; cursor[i] = ex; }
    if (i == N_NODES - 1) off[N_NODES] = ex + v;
}

// scatter: ONLY csr_src (4B/edge scattered). exp factors computed inline in agg.
__global__ void scatter_kernel(const int* __restrict__ ei, int* __restrict__ cursor,
                               int* __restrict__ csr_src) {
    int i = blockIdx.x * blockDim.x + threadIdx.x;
    int stride = gridDim.x * blockDim.x;
    for (; i < EP; i += stride) {
        int src, dst;
        if (i < E_EDGES) { src = ei[i]; dst = ei[E_EDGES + i]; }
        else             { src = i - E_EDGES; dst = src; }
        int pos = atomicAdd(&cursor[dst], 1);
        csr_src[pos] = src;
    }
}

// ---------------- Layer 1 GEMM: 64 nodes/block, 8n x 4c register tile ----------------

__global__ __launch_bounds__(256) void gemm1_kernel(
        const float* __restrict__ x, const float* __restrict__ W1,
        const float* __restrict__ att_src1, const float* __restrict__ att_dst1,
        float* __restrict__ xw1, float* __restrict__ as1, float* __restrict__ ad1) {
    __shared__ float xt[128 * 66];          // xt[k][node], pad 2
    int tid = threadIdx.x;
    int base = blockIdx.x * 64;
#pragma unroll 4
    for (int it = 0; it < 32; ++it) {
        int e = it * 256 + tid;
        int nn = e >> 7, c = e & 127;
        float v = (base + nn < N_NODES) ? x[(size_t)base * 128 + e] : 0.f;
        xt[c * 66 + nn] = v;
    }
    __syncthreads();
    int cg = tid & 31, ng = tid >> 5;
    float acc[8][4];
#pragma unroll
    for (int i = 0; i < 8; i++)
#pragma unroll
        for (int j = 0; j < 4; j++) acc[i][j] = 0.f;

#pragma unroll 4
    for (int k = 0; k < 128; ++k) {
        float4 w = *(const float4*)&W1[k * 128 + 4 * cg];
        const float* xr = &xt[k * 66 + 8 * ng];
        float2 a0 = *(const float2*)&xr[0];
        float2 a1 = *(const float2*)&xr[2];
        float2 a2 = *(const float2*)&xr[4];
        float2 a3 = *(const float2*)&xr[6];
        float xv[8] = {a0.x, a0.y, a1.x, a1.y, a2.x, a2.y, a3.x, a3.y};
#pragma unroll
        for (int i = 0; i < 8; i++) {
            acc[i][0] = fmaf(xv[i], w.x, acc[i][0]);
            acc[i][1] = fmaf(xv[i], w.y, acc[i][1]);
            acc[i][2] = fmaf(xv[i], w.z, acc[i][2]);
            acc[i][3] = fmaf(xv[i], w.w, acc[i][3]);
        }
    }
    int c0 = 4 * cg;
    float s0 = att_src1[c0], s1 = att_src1[c0 + 1], s2 = att_src1[c0 + 2], s3 = att_src1[c0 + 3];
    float d0 = att_dst1[c0], d1 = att_dst1[c0 + 1], d2 = att_dst1[c0 + 2], d3 = att_dst1[c0 + 3];
#pragma unroll
    for (int i = 0; i < 8; i++) {
        int n = base + 8 * ng + i;
        bool ok = n < N_NODES;
        if (ok) *(float4*)&xw1[(size_t)n * 128 + c0] =
            make_float4(acc[i][0], acc[i][1], acc[i][2], acc[i][3]);
        float ps = acc[i][0] * s0 + acc[i][1] * s1 + acc[i][2] * s2 + acc[i][3] * s3;
        float pd = acc[i][0] * d0 + acc[i][1] * d1 + acc[i][2] * d2 + acc[i][3] * d3;
#pragma unroll
        for (int m = 8; m >= 1; m >>= 1) {
            ps += __shfl_xor(ps, m);
            pd += __shfl_xor(pd, m);
        }
        if (ok && (cg == 0 || cg == 16)) {
            int h = cg >> 4;
            as1[n * 2 + h] = ps;
            ad1[n * 2 + h] = pd;
        }
    }
}

// ---------------- Layer 1 aggregation: one wave per node, inline exp ----------------

__global__ __launch_bounds__(256) void agg1_kernel(
        const int* __restrict__ off, const int* __restrict__ csr_src,
        const float* __restrict__ as1, const float* __restrict__ ad1,
        const float* __restrict__ xw1, const float* __restrict__ b1,
        float* __restrict__ h) {
    int wv = threadIdx.x >> 6, lane = threadIdx.x & 63;
    int n = blockIdx.x * 4 + wv;
    if (n >= N_NODES) return;
    int s = off[n], e = off[n + 1];
    float adn0 = ad1[2 * n], adn1 = ad1[2 * n + 1];
    float acc0 = 0.f, acc1 = 0.f, sum0 = 0.f, sum1 = 0.f;
    for (int b = s; b < e; b += 64) {
        int cnt = min(64, e - b);
        int l = lane < cnt ? lane : cnt - 1;
        int srcv = csr_src[b + l];
        float2 a = *(const float2*)&as1[2 * srcv];   // L2-resident gather
        float e0 = a.x + adn0; e0 = e0 > 0.f ? e0 : NEG_SLOPE * e0;
        float e1 = a.y + adn1; e1 = e1 > 0.f ? e1 : NEG_SLOPE * e1;
        float f0v = (lane < cnt) ? __expf(e0) : 0.f;
        float f1v = (lane < cnt) ? __expf(e1) : 0.f;
        float r0 = f0v, r1 = f1v;
#pragma unroll
        for (int m = 32; m >= 1; m >>= 1) { r0 += __shfl_xor(r0, m); r1 += __shfl_xor(r1, m); }
        sum0 += r0; sum1 += r1;
        for (int jj = 0; jj < cnt; jj++) {
            int src = __shfl(srcv, jj);
            float f0 = __shfl(f0v, jj);
            float f1 = __shfl(f1v, jj);
            float f = (lane < 32) ? f0 : f1;
            float2 row = *(const float2*)&xw1[(size_t)src * 128 + 2 * lane];
            acc0 = fmaf(row.x, f, acc0);
            acc1 = fmaf(row.y, f, acc1);
        }
    }
    float sum = (lane < 32) ? sum0 : sum1;
    int c = 2 * lane;
    float v0 = acc0 / sum + b1[c];
    float v1 = acc1 / sum + b1[c + 1];
    float2 o; o.x = v0 > 0.f ? v0 : 0.f; o.y = v1 > 0.f ? v1 : 0.f;
    *(float2*)&h[(size_t)n * 128 + c] = o;
}

// ---------------- Layer 2 GEMM: 64 nodes/block, 4n x 4c tile ----------------

__global__ __launch_bounds__(256) void gemm2_kernel(
        const float* __restrict__ h, const float* __restrict__ W2,
        const float* __restrict__ att_src2, const float* __restrict__ att_dst2,
        float* __restrict__ xw2, float* __restrict__ as2, float* __restrict__ ad2) {
    __shared__ float xt[128 * 66];
    int tid = threadIdx.x;
    int base = blockIdx.x * 64;
#pragma unroll 4
    for (int it = 0; it < 32; ++it) {
        int e = it * 256 + tid;
        int nn = e >> 7, c = e & 127;
        float v = (base + nn < N_NODES) ? h[(size_t)base * 128 + e] : 0.f;
        xt[c * 66 + nn] = v;
    }
    __syncthreads();
    int cg = tid & 15, ng = tid >> 4;
    float acc[4][4];
#pragma unroll
    for (int i = 0; i < 4; i++)
#pragma unroll
        for (int j = 0; j < 4; j++) acc[i][j] = 0.f;

#pragma unroll 4
    for (int k = 0; k < 128; ++k) {
        float4 w = *(const float4*)&W2[k * 64 + 4 * cg];
        const float* xr = &xt[k * 66 + 4 * ng];
        float2 a0 = *(const float2*)&xr[0];
        float2 a1 = *(const float2*)&xr[2];
        float xv[4] = {a0.x, a0.y, a1.x, a1.y};
#pragma unroll
        for (int i = 0; i < 4; i++) {
            acc[i][0] = fmaf(xv[i], w.x, acc[i][0]);
            acc[i][1] = fmaf(xv[i], w.y, acc[i][1]);
            acc[i][2] = fmaf(xv[i], w.z, acc[i][2]);
            acc[i][3] = fmaf(xv[i], w.w, acc[i][3]);
        }
    }
    int c0 = 4 * cg;
    float s0 = att_src2[c0], s1 = att_src2[c0 + 1], s2 = att_src2[c0 + 2], s3 = att_src2[c0 + 3];
    float d0 = att_dst2[c0], d1 = att_dst2[c0 + 1], d2 = att_dst2[c0 + 2], d3 = att_dst2[c0 + 3];
#pragma unroll
    for (int i = 0; i < 4; i++) {
        int n = base + 4 * ng + i;
        bool ok = n < N_NODES;
        if (ok) *(float4*)&xw2[(size_t)n * 64 + c0] =
            make_float4(acc[i][0], acc[i][1], acc[i][2], acc[i][3]);
        float ps = acc[i][0] * s0 + acc[i][1] * s1 + acc[i][2] * s2 + acc[i][3] * s3;
        float pd = acc[i][0] * d0 + acc[i][1] * d1 + acc[i][2] * d2 + acc[i][3] * d3;
#pragma unroll
        for (int m = 8; m >= 1; m >>= 1) {
            ps += __shfl_xor(ps, m);
            pd += __shfl_xor(pd, m);
        }
        if (ok && cg == 0) { as2[n] = ps; ad2[n] = pd; }
    }
}

// ---------------- Layer 2 aggregation: inline exp ----------------

__global__ __launch_bounds__(256) void agg2_kernel(
        const int* __restrict__ off, const int* __restrict__ csr_src,
        const float* __restrict__ as2, const float* __restrict__ ad2,
        const float* __restrict__ xw2, const float* __restrict__ b2,
        float* __restrict__ z) {
    int wv = threadIdx.x >> 6, lane = threadIdx.x & 63;
    int n = blockIdx.x * 4 + wv;
    if (n >= N_NODES) return;
    int s = off[n], e = off[n + 1];
    float adn = ad2[n];
    float acc = 0.f, sum = 0.f;
    for (int b = s; b < e; b += 64) {
        int cnt = min(64, e - b);
        int l = lane < cnt ? lane : cnt - 1;
        int srcv = csr_src[b + l];
        float a = as2[srcv];                         // L2-resident gather
        float ev = a + adn; ev = ev > 0.f ? ev : NEG_SLOPE * ev;
        float fv = (lane < cnt) ? __expf(ev) : 0.f;
        float r = fv;
#pragma unroll
        for (int m = 32; m >= 1; m >>= 1) r += __shfl_xor(r, m);
        sum += r;
        for (int jj = 0; jj < cnt; jj++) {
            int src = __shfl(srcv, jj);
            float f = __shfl(fv, jj);
            acc = fmaf(xw2[(size_t)src * 64 + lane], f, acc);
        }
    }
    z[(size_t)n * 64 + lane] = acc / sum + b2[lane];
}

// ---------------- Link decode ----------------

__global__ __launch_bounds__(256) void decode_kernel(
        const int* __restrict__ pos_ei, const int* __restrict__ neg_ei,
        const float* __restrict__ z, const float* __restrict__ lw,
        const float* __restrict__ lb, float* __restrict__ out) {
    int wv = threadIdx.x >> 6, lane = threadIdx.x & 63;
    int idx = blockIdx.x * 4 + wv;
    if (idx >= 2 * P_CAND) return;
    const int* ei; int p;
    if (idx < P_CAND) { ei = pos_ei; p = idx; }
    else              { ei = neg_ei; p = idx - P_CAND; }
    int sN = ei[p], dN = ei[P_CAND + p];
    float2 zz, ww;
    if (lane < 32) {
        zz = *(const float2*)&z[(size_t)sN * 64 + 2 * lane];
        ww = *(const float2*)&lw[2 * lane];
    } else {
        int q = lane - 32;
        zz = *(const float2*)&z[(size_t)dN * 64 + 2 * q];
        ww = *(const float2*)&lw[64 + 2 * q];
    }
    float v = zz.x * ww.x + zz.y * ww.y;
#pragma unroll
    for (int m = 32; m >= 1; m >>= 1) v += __shfl_xor(v, m);
    if (lane == 0) out[idx] = v + lb[0];
}

// ---------------- launch ----------------

extern "C" void kernel_launch(void* const* d_in, const int* in_sizes, int n_in,
                              void* d_out, int out_size, void* d_ws, size_t ws_size,
                              hipStream_t stream) {
    const float* x        = (const float*)d_in[0];
    const int*   ei       = (const int*)d_in[1];
    const int*   pos_ei   = (const int*)d_in[3];
    const int*   neg_ei   = (const int*)d_in[4];
    const float* W1       = (const float*)d_in[5];
    const float* att_src1 = (const float*)d_in[6];
    const float* att_dst1 = (const float*)d_in[7];
    const float* b1       = (const float*)d_in[8];
    const float* W2       = (const float*)d_in[9];
    const float* att_src2 = (const float*)d_in[10];
    const float* att_dst2 = (const float*)d_in[11];
    const float* b2       = (const float*)d_in[12];
    const float* lw       = (const float*)d_in[13];
    const float* lb       = (const float*)d_in[14];
    float* out = (float*)d_out;

    char* ws = (char*)d_ws;
    size_t o = 0;
    auto alloc = [&](size_t bytes) -> char* {
        char* p = ws + o;
        o += (bytes + 511) & ~(size_t)511;
        return p;
    };
    float*  xw1    = (float*)alloc((size_t)N_NODES * 128 * 4);  // reused: xw2 | z
    float*  h      = (float*)alloc((size_t)N_NODES * 128 * 4);
    float*  as1    = (float*)alloc((size_t)N_NODES * 2 * 4);
    float*  ad1    = (float*)alloc((size_t)N_NODES * 2 * 4);
    float*  as2    = (float*)alloc((size_t)N_NODES * 4);
    float*  ad2    = (float*)alloc((size_t)N_NODES * 4);
    int*    deg    = (int*)alloc((size_t)N_NODES * 4);
    int*    off    = (int*)alloc((size_t)(N_NODES + 1) * 4);
    int*    cursor = (int*)alloc((size_t)N_NODES * 4);
    int*    bsum   = (int*)alloc((size_t)SCAN_NB * 4);
    int*    bbase  = (int*)alloc((size_t)SCAN_NB * 4);
    int*    csr    = (int*)alloc((size_t)EP * 4);
    float*  xw2 = xw1;
    float*  z   = xw1 + (size_t)N_NODES * 64;

    hipMemsetAsync(deg, 0, (size_t)N_NODES * 4, stream);
    deg_kernel<<<2048, 256, 0, stream>>>(ei, deg);
    partial_kernel<<<SCAN_NB, 256, 0, stream>>>(deg, bsum);
    scanb_kernel<<<1, 512, 0, stream>>>(bsum, bbase);
    offs_kernel<<<SCAN_NB, 256, 0, stream>>>(deg, bbase, off, cursor);
    scatter_kernel<<<2048, 256, 0, stream>>>(ei, cursor, csr);
    gemm1_kernel<<<(N_NODES + 63) / 64, 256, 0, stream>>>(x, W1, att_src1, att_dst1, xw1, as1, ad1);
    agg1_kernel<<<(N_NODES + 3) / 4, 256, 0, stream>>>(off, csr, as1, ad1, xw1, b1, h);
    gemm2_kernel<<<(N_NODES + 63) / 64, 256, 0, stream>>>(h, W2, att_src2, att_dst2, xw2, as2, ad2);
    agg2_kernel<<<(N_NODES + 3) / 4, 256, 0, stream>>>(off, csr, as2, ad2, xw2, b2, z);
    decode_kernel<<<(2 * P_CAND + 3) / 4, 256, 0, stream>>>(pos_ei, neg_ei, z, lw, lb, out);
}

// Round 5
// 666.477 us; speedup vs baseline: 1.9461x; 1.2172x over previous
//
#include <hip/hip_runtime.h>

#define N_NODES 100000
#define E_EDGES 1600000
#define EP      (E_EDGES + N_NODES)   // edges + self loops = 1,700,000
#define P_CAND  262144
#define IN_C    128
#define HID     64
#define NEG_SLOPE 0.2f

#define NBIN  196            // ceil(100000/512) bins of 512 nodes
#define NB2   256            // blocks for hist/scatterbin
#define EPB   ((EP + NB2 - 1) / NB2)   // 6641 edges per block
#define NTOT  (NBIN * NB2)   // 50176 (= 1024*49)

// ---------------- CSR build: deterministic 2-level counting sort ----------------

// pass 1: per-(block,bin) histogram of dst>>9
__global__ __launch_bounds__(256) void hist_kernel(const int* __restrict__ ei,
                                                   int* __restrict__ hist) {
    __shared__ int lh[NBIN];
    for (int t = threadIdx.x; t < NBIN; t += 256) lh[t] = 0;
    __syncthreads();
    int start = blockIdx.x * EPB;
    int end = min(start + EPB, EP);
    for (int i = start + threadIdx.x; i < end; i += 256) {
        int dst = (i < E_EDGES) ? ei[E_EDGES + i] : (i - E_EDGES);
        atomicAdd(&lh[dst >> 9], 1);
    }
    __syncthreads();
    for (int t = threadIdx.x; t < NBIN; t += 256) hist[t * NB2 + blockIdx.x] = lh[t];
}

// pass 2: exclusive scan of all 50176 (bin,block) counts (bin-major)
__global__ __launch_bounds__(1024) void scan2_kernel(const int* __restrict__ hist,
                                                     int* __restrict__ histS) {
    __shared__ int s[1024];
    int t = threadIdx.x;
    int b0 = t * 49;                       // 1024*49 == 50176
    int sum = 0;
    for (int i = 0; i < 49; i++) sum += hist[b0 + i];
    s[t] = sum;
    __syncthreads();
    for (int d = 1; d < 1024; d <<= 1) {
        int v = (t >= d) ? s[t - d] : 0;
        __syncthreads();
        s[t] += v;
        __syncthreads();
    }
    int run = s[t] - sum;                  // exclusive base for this thread's range
    for (int i = 0; i < 49; i++) { int hv = hist[b0 + i]; histS[b0 + i] = run; run += hv; }
}

// pass 3: scatter edges into private per-(block,bin) ranges; pack (dstlow<<17)|src
__global__ __launch_bounds__(256) void scatterbin_kernel(const int* __restrict__ ei,
                                                         const int* __restrict__ histS,
                                                         unsigned* __restrict__ binned) {
    __shared__ int cur[NBIN];
    for (int t = threadIdx.x; t < NBIN; t += 256) cur[t] = histS[t * NB2 + blockIdx.x];
    __syncthreads();
    int start = blockIdx.x * EPB;
    int end = min(start + EPB, EP);
    for (int i = start + threadIdx.x; i < end; i += 256) {
        int src, dst;
        if (i < E_EDGES) { src = ei[i]; dst = ei[E_EDGES + i]; }
        else             { src = i - E_EDGES; dst = src; }
        int pos = atomicAdd(&cur[dst >> 9], 1);
        binned[pos] = (unsigned)src | ((unsigned)(dst & 511) << 17);
    }
}

// pass 4: one block per bin: local 512-node histogram -> scan -> off[] + csr_src
__global__ __launch_bounds__(1024) void binsort_kernel(const unsigned* __restrict__ binned,
                                                       const int* __restrict__ histS,
                                                       int* __restrict__ off,
                                                       int* __restrict__ csr) {
    __shared__ int lh[512];
    __shared__ int lsc[512];
    int b = blockIdx.x, t = threadIdx.x;
    int base = histS[b * NB2];
    int endv = (b == NBIN - 1) ? EP : histS[(b + 1) * NB2];
    if (t < 512) lh[t] = 0;
    __syncthreads();
    for (int i = base + t; i < endv; i += 1024)
        atomicAdd(&lh[binned[i] >> 17], 1);
    __syncthreads();
    if (t < 512) lsc[t] = lh[t];
    __syncthreads();
    for (int d = 1; d < 512; d <<= 1) {
        int v = (t >= d && t < 512) ? lsc[t - d] : 0;
        __syncthreads();
        if (t < 512) lsc[t] += v;
        __syncthreads();
    }
    if (t < 512) {
        int ex = lsc[t] - lh[t];           // exclusive local offset
        int node = b * 512 + t;
        if (node <= N_NODES) off[node] = base + ex;  // node==N -> base+cnt == EP
        lh[t] = base + ex;                 // becomes the scatter cursor
    }
    __syncthreads();
    for (int i = base + t; i < endv; i += 1024) {
        unsigned v = binned[i];
        int pos = atomicAdd(&lh[v >> 17], 1);
        csr[pos] = (int)(v & 0x1FFFFu);
    }
}

// ---------------- Layer 1 GEMM: 64 nodes/block, 8n x 4c register tile ----------------

__global__ __launch_bounds__(256) void gemm1_kernel(
        const float* __restrict__ x, const float* __restrict__ W1,
        const float* __restrict__ att_src1, const float* __restrict__ att_dst1,
        float* __restrict__ xw1, float* __restrict__ as1, float* __restrict__ ad1) {
    __shared__ float xt[128 * 66];          // xt[k][node], pad 2
    int tid = threadIdx.x;
    int base = blockIdx.x * 64;
#pragma unroll 4
    for (int it = 0; it < 32; ++it) {
        int e = it * 256 + tid;
        int nn = e >> 7, c = e & 127;
        float v = (base + nn < N_NODES) ? x[(size_t)base * 128 + e] : 0.f;
        xt[c * 66 + nn] = v;
    }
    __syncthreads();
    int cg = tid & 31, ng = tid >> 5;
    float acc[8][4];
#pragma unroll
    for (int i = 0; i < 8; i++)
#pragma unroll
        for (int j = 0; j < 4; j++) acc[i][j] = 0.f;

#pragma unroll 4
    for (int k = 0; k < 128; ++k) {
        float4 w = *(const float4*)&W1[k * 128 + 4 * cg];
        const float* xr = &xt[k * 66 + 8 * ng];
        float2 a0 = *(const float2*)&xr[0];
        float2 a1 = *(const float2*)&xr[2];
        float2 a2 = *(const float2*)&xr[4];
        float2 a3 = *(const float2*)&xr[6];
        float xv[8] = {a0.x, a0.y, a1.x, a1.y, a2.x, a2.y, a3.x, a3.y};
#pragma unroll
        for (int i = 0; i < 8; i++) {
            acc[i][0] = fmaf(xv[i], w.x, acc[i][0]);
            acc[i][1] = fmaf(xv[i], w.y, acc[i][1]);
            acc[i][2] = fmaf(xv[i], w.z, acc[i][2]);
            acc[i][3] = fmaf(xv[i], w.w, acc[i][3]);
        }
    }
    int c0 = 4 * cg;
    float s0 = att_src1[c0], s1 = att_src1[c0 + 1], s2 = att_src1[c0 + 2], s3 = att_src1[c0 + 3];
    float d0 = att_dst1[c0], d1 = att_dst1[c0 + 1], d2 = att_dst1[c0 + 2], d3 = att_dst1[c0 + 3];
#pragma unroll
    for (int i = 0; i < 8; i++) {
        int n = base + 8 * ng + i;
        bool ok = n < N_NODES;
        if (ok) *(float4*)&xw1[(size_t)n * 128 + c0] =
            make_float4(acc[i][0], acc[i][1], acc[i][2], acc[i][3]);
        float ps = acc[i][0] * s0 + acc[i][1] * s1 + acc[i][2] * s2 + acc[i][3] * s3;
        float pd = acc[i][0] * d0 + acc[i][1] * d1 + acc[i][2] * d2 + acc[i][3] * d3;
#pragma unroll
        for (int m = 8; m >= 1; m >>= 1) {
            ps += __shfl_xor(ps, m);
            pd += __shfl_xor(pd, m);
        }
        if (ok && (cg == 0 || cg == 16)) {
            int h = cg >> 4;
            as1[n * 2 + h] = ps;
            ad1[n * 2 + h] = pd;
        }
    }
}

// ---------------- Layer 1 aggregation: one wave per node, inline exp ----------------

__global__ __launch_bounds__(256) void agg1_kernel(
        const int* __restrict__ off, const int* __restrict__ csr_src,
        const float* __restrict__ as1, const float* __restrict__ ad1,
        const float* __restrict__ xw1, const float* __restrict__ b1,
        float* __restrict__ h) {
    int wv = threadIdx.x >> 6, lane = threadIdx.x & 63;
    int n = blockIdx.x * 4 + wv;
    if (n >= N_NODES) return;
    int s = off[n], e = off[n + 1];
    float adn0 = ad1[2 * n], adn1 = ad1[2 * n + 1];
    float acc0 = 0.f, acc1 = 0.f, sum0 = 0.f, sum1 = 0.f;
    for (int b = s; b < e; b += 64) {
        int cnt = min(64, e - b);
        int l = lane < cnt ? lane : cnt - 1;
        int srcv = csr_src[b + l];
        float2 a = *(const float2*)&as1[2 * srcv];   // L2-resident gather
        float e0 = a.x + adn0; e0 = e0 > 0.f ? e0 : NEG_SLOPE * e0;
        float e1 = a.y + adn1; e1 = e1 > 0.f ? e1 : NEG_SLOPE * e1;
        float f0v = (lane < cnt) ? __expf(e0) : 0.f;
        float f1v = (lane < cnt) ? __expf(e1) : 0.f;
        float r0 = f0v, r1 = f1v;
#pragma unroll
        for (int m = 32; m >= 1; m >>= 1) { r0 += __shfl_xor(r0, m); r1 += __shfl_xor(r1, m); }
        sum0 += r0; sum1 += r1;
        for (int jj = 0; jj < cnt; jj++) {
            int src = __shfl(srcv, jj);
            float f0 = __shfl(f0v, jj);
            float f1 = __shfl(f1v, jj);
            float f = (lane < 32) ? f0 : f1;
            float2 row = *(const float2*)&xw1[(size_t)src * 128 + 2 * lane];
            acc0 = fmaf(row.x, f, acc0);
            acc1 = fmaf(row.y, f, acc1);
        }
    }
    float sum = (lane < 32) ? sum0 : sum1;
    int c = 2 * lane;
    float v0 = acc0 / sum + b1[c];
    float v1 = acc1 / sum + b1[c + 1];
    float2 o; o.x = v0 > 0.f ? v0 : 0.f; o.y = v1 > 0.f ? v1 : 0.f;
    *(float2*)&h[(size_t)n * 128 + c] = o;
}

// ---------------- Layer 2 GEMM: 64 nodes/block, 4n x 4c tile ----------------

__global__ __launch_bounds__(256) void gemm2_kernel(
        const float* __restrict__ h, const float* __restrict__ W2,
        const float* __restrict__ att_src2, const float* __restrict__ att_dst2,
        float* __restrict__ xw2, float* __restrict__ as2, float* __restrict__ ad2) {
    __shared__ float xt[128 * 66];
    int tid = threadIdx.x;
    int base = blockIdx.x * 64;
#pragma unroll 4
    for (int it = 0; it < 32; ++it) {
        int e = it * 256 + tid;
        int nn = e >> 7, c = e & 127;
        float v = (base + nn < N_NODES) ? h[(size_t)base * 128 + e] : 0.f;
        xt[c * 66 + nn] = v;
    }
    __syncthreads();
    int cg = tid & 15, ng = tid >> 4;
    float acc[4][4];
#pragma unroll
    for (int i = 0; i < 4; i++)
#pragma unroll
        for (int j = 0; j < 4; j++) acc[i][j] = 0.f;

#pragma unroll 4
    for (int k = 0; k < 128; ++k) {
        float4 w = *(const float4*)&W2[k * 64 + 4 * cg];
        const float* xr = &xt[k * 66 + 4 * ng];
        float2 a0 = *(const float2*)&xr[0];
        float2 a1 = *(const float2*)&xr[2];
        float xv[4] = {a0.x, a0.y, a1.x, a1.y};
#pragma unroll
        for (int i = 0; i < 4; i++) {
            acc[i][0] = fmaf(xv[i], w.x, acc[i][0]);
            acc[i][1] = fmaf(xv[i], w.y, acc[i][1]);
            acc[i][2] = fmaf(xv[i], w.z, acc[i][2]);
            acc[i][3] = fmaf(xv[i], w.w, acc[i][3]);
        }
    }
    int c0 = 4 * cg;
    float s0 = att_src2[c0], s1 = att_src2[c0 + 1], s2 = att_src2[c0 + 2], s3 = att_src2[c0 + 3];
    float d0 = att_dst2[c0], d1 = att_dst2[c0 + 1], d2 = att_dst2[c0 + 2], d3 = att_dst2[c0 + 3];
#pragma unroll
    for (int i = 0; i < 4; i++) {
        int n = base + 4 * ng + i;
        bool ok = n < N_NODES;
        if (ok) *(float4*)&xw2[(size_t)n * 64 + c0] =
            make_float4(acc[i][0], acc[i][1], acc[i][2], acc[i][3]);
        float ps = acc[i][0] * s0 + acc[i][1] * s1 + acc[i][2] * s2 + acc[i][3] * s3;
        float pd = acc[i][0] * d0 + acc[i][1] * d1 + acc[i][2] * d2 + acc[i][3] * d3;
#pragma unroll
        for (int m = 8; m >= 1; m >>= 1) {
            ps += __shfl_xor(ps, m);
            pd += __shfl_xor(pd, m);
        }
        if (ok && cg == 0) { as2[n] = ps; ad2[n] = pd; }
    }
}

// ---------------- Layer 2 aggregation: inline exp ----------------

__global__ __launch_bounds__(256) void agg2_kernel(
        const int* __restrict__ off, const int* __restrict__ csr_src,
        const float* __restrict__ as2, const float* __restrict__ ad2,
        const float* __restrict__ xw2, const float* __restrict__ b2,
        float* __restrict__ z) {
    int wv = threadIdx.x >> 6, lane = threadIdx.x & 63;
    int n = blockIdx.x * 4 + wv;
    if (n >= N_NODES) return;
    int s = off[n], e = off[n + 1];
    float adn = ad2[n];
    float acc = 0.f, sum = 0.f;
    for (int b = s; b < e; b += 64) {
        int cnt = min(64, e - b);
        int l = lane < cnt ? lane : cnt - 1;
        int srcv = csr_src[b + l];
        float a = as2[srcv];                         // L2-resident gather
        float ev = a + adn; ev = ev > 0.f ? ev : NEG_SLOPE * ev;
        float fv = (lane < cnt) ? __expf(ev) : 0.f;
        float r = fv;
#pragma unroll
        for (int m = 32; m >= 1; m >>= 1) r += __shfl_xor(r, m);
        sum += r;
        for (int jj = 0; jj < cnt; jj++) {
            int src = __shfl(srcv, jj);
            float f = __shfl(fv, jj);
            acc = fmaf(xw2[(size_t)src * 64 + lane], f, acc);
        }
    }
    z[(size_t)n * 64 + lane] = acc / sum + b2[lane];
}

// ---------------- Link decode ----------------

__global__ __launch_bounds__(256) void decode_kernel(
        const int* __restrict__ pos_ei, const int* __restrict__ neg_ei,
        const float* __restrict__ z, const float* __restrict__ lw,
        const float* __restrict__ lb, float* __restrict__ out) {
    int wv = threadIdx.x >> 6, lane = threadIdx.x & 63;
    int idx = blockIdx.x * 4 + wv;
    if (idx >= 2 * P_CAND) return;
    const int* ei; int p;
    if (idx < P_CAND) { ei = pos_ei; p = idx; }
    else              { ei = neg_ei; p = idx - P_CAND; }
    int sN = ei[p], dN = ei[P_CAND + p];
    float2 zz, ww;
    if (lane < 32) {
        zz = *(const float2*)&z[(size_t)sN * 64 + 2 * lane];
        ww = *(const float2*)&lw[2 * lane];
    } else {
        int q = lane - 32;
        zz = *(const float2*)&z[(size_t)dN * 64 + 2 * q];
        ww = *(const float2*)&lw[64 + 2 * q];
    }
    float v = zz.x * ww.x + zz.y * ww.y;
#pragma unroll
    for (int m = 32; m >= 1; m >>= 1) v += __shfl_xor(v, m);
    if (lane == 0) out[idx] = v + lb[0];
}

// ---------------- launch ----------------

extern "C" void kernel_launch(void* const* d_in, const int* in_sizes, int n_in,
                              void* d_out, int out_size, void* d_ws, size_t ws_size,
                              hipStream_t stream) {
    const float* x        = (const float*)d_in[0];
    const int*   ei       = (const int*)d_in[1];
    const int*   pos_ei   = (const int*)d_in[3];
    const int*   neg_ei   = (const int*)d_in[4];
    const float* W1       = (const float*)d_in[5];
    const float* att_src1 = (const float*)d_in[6];
    const float* att_dst1 = (const float*)d_in[7];
    const float* b1       = (const float*)d_in[8];
    const float* W2       = (const float*)d_in[9];
    const float* att_src2 = (const float*)d_in[10];
    const float* att_dst2 = (const float*)d_in[11];
    const float* b2       = (const float*)d_in[12];
    const float* lw       = (const float*)d_in[13];
    const float* lb       = (const float*)d_in[14];
    float* out = (float*)d_out;

    char* ws = (char*)d_ws;
    size_t o = 0;
    auto alloc = [&](size_t bytes) -> char* {
        char* p = ws + o;
        o += (bytes + 511) & ~(size_t)511;
        return p;
    };
    float*    xw1   = (float*)alloc((size_t)N_NODES * 128 * 4);  // reused: xw2 | z
    float*    h     = (float*)alloc((size_t)N_NODES * 128 * 4);
    float*    as1   = (float*)alloc((size_t)N_NODES * 2 * 4);
    float*    ad1   = (float*)alloc((size_t)N_NODES * 2 * 4);
    float*    as2   = (float*)alloc((size_t)N_NODES * 4);
    float*    ad2   = (float*)alloc((size_t)N_NODES * 4);
    int*      off   = (int*)alloc((size_t)(N_NODES + 1) * 4);
    int*      hist  = (int*)alloc((size_t)NTOT * 4);
    int*      histS = (int*)alloc((size_t)NTOT * 4);
    unsigned* binned= (unsigned*)alloc((size_t)EP * 4);
    int*      csr   = (int*)alloc((size_t)EP * 4);
    float*    xw2 = xw1;
    float*    z   = xw1 + (size_t)N_NODES * 64;

    hist_kernel<<<NB2, 256, 0, stream>>>(ei, hist);
    scan2_kernel<<<1, 1024, 0, stream>>>(hist, histS);
    scatterbin_kernel<<<NB2, 256, 0, stream>>>(ei, histS, binned);
    binsort_kernel<<<NBIN, 1024, 0, stream>>>(binned, histS, off, csr);
    gemm1_kernel<<<(N_NODES + 63) / 64, 256, 0, stream>>>(x, W1, att_src1, att_dst1, xw1, as1, ad1);
    agg1_kernel<<<(N_NODES + 3) / 4, 256, 0, stream>>>(off, csr, as1, ad1, xw1, b1, h);
    gemm2_kernel<<<(N_NODES + 63) / 64, 256, 0, stream>>>(h, W2, att_src2, att_dst2, xw2, as2, ad2);
    agg2_kernel<<<(N_NODES + 3) / 4, 256, 0, stream>>>(off, csr, as2, ad2, xw2, b2, z);
    decode_kernel<<<(2 * P_CAND + 3) / 4, 256, 0, stream>>>(pos_ei, neg_ei, z, lw, lb, out);
}

// Round 6
// 567.576 us; speedup vs baseline: 2.2852x; 1.1743x over previous
//
#include <hip/hip_runtime.h>

#define N_NODES 100000
#define E_EDGES 1600000
#define EP      (E_EDGES + N_NODES)   // edges + self loops = 1,700,000
#define P_CAND  262144
#define IN_C    128
#define HID     64
#define NEG_SLOPE 0.2f

#define NBIN  196            // ceil(100000/512) bins of 512 nodes
#define NB2   256            // blocks for hist/scatterbin
#define EPB   ((EP + NB2 - 1) / NB2)   // 6641 edges per block
#define NTOT  (NBIN * NB2)   // 50176 (= 1024*49)

typedef _Float16 half4v __attribute__((ext_vector_type(4)));

// ---------------- CSR build: deterministic 2-level counting sort ----------------

__global__ __launch_bounds__(256) void hist_kernel(const int* __restrict__ ei,
                                                   int* __restrict__ hist) {
    __shared__ int lh[NBIN];
    for (int t = threadIdx.x; t < NBIN; t += 256) lh[t] = 0;
    __syncthreads();
    int start = blockIdx.x * EPB;
    int end = min(start + EPB, EP);
    for (int i = start + threadIdx.x; i < end; i += 256) {
        int dst = (i < E_EDGES) ? ei[E_EDGES + i] : (i - E_EDGES);
        atomicAdd(&lh[dst >> 9], 1);
    }
    __syncthreads();
    for (int t = threadIdx.x; t < NBIN; t += 256) hist[t * NB2 + blockIdx.x] = lh[t];
}

__global__ __launch_bounds__(1024) void scan2_kernel(const int* __restrict__ hist,
                                                     int* __restrict__ histS) {
    __shared__ int s[1024];
    int t = threadIdx.x;
    int b0 = t * 49;                       // 1024*49 == 50176
    int sum = 0;
    for (int i = 0; i < 49; i++) sum += hist[b0 + i];
    s[t] = sum;
    __syncthreads();
    for (int d = 1; d < 1024; d <<= 1) {
        int v = (t >= d) ? s[t - d] : 0;
        __syncthreads();
        s[t] += v;
        __syncthreads();
    }
    int run = s[t] - sum;
    for (int i = 0; i < 49; i++) { int hv = hist[b0 + i]; histS[b0 + i] = run; run += hv; }
}

__global__ __launch_bounds__(256) void scatterbin_kernel(const int* __restrict__ ei,
                                                         const int* __restrict__ histS,
                                                         unsigned* __restrict__ binned) {
    __shared__ int cur[NBIN];
    for (int t = threadIdx.x; t < NBIN; t += 256) cur[t] = histS[t * NB2 + blockIdx.x];
    __syncthreads();
    int start = blockIdx.x * EPB;
    int end = min(start + EPB, EP);
    for (int i = start + threadIdx.x; i < end; i += 256) {
        int src, dst;
        if (i < E_EDGES) { src = ei[i]; dst = ei[E_EDGES + i]; }
        else             { src = i - E_EDGES; dst = src; }
        int pos = atomicAdd(&cur[dst >> 9], 1);
        binned[pos] = (unsigned)src | ((unsigned)(dst & 511) << 17);
    }
}

__global__ __launch_bounds__(1024) void binsort_kernel(const unsigned* __restrict__ binned,
                                                       const int* __restrict__ histS,
                                                       int* __restrict__ off,
                                                       int* __restrict__ csr) {
    __shared__ int lh[512];
    __shared__ int lsc[512];
    int b = blockIdx.x, t = threadIdx.x;
    int base = histS[b * NB2];
    int endv = (b == NBIN - 1) ? EP : histS[(b + 1) * NB2];
    if (t < 512) lh[t] = 0;
    __syncthreads();
    for (int i = base + t; i < endv; i += 1024)
        atomicAdd(&lh[binned[i] >> 17], 1);
    __syncthreads();
    if (t < 512) lsc[t] = lh[t];
    __syncthreads();
    for (int d = 1; d < 512; d <<= 1) {
        int v = (t >= d && t < 512) ? lsc[t - d] : 0;
        __syncthreads();
        if (t < 512) lsc[t] += v;
        __syncthreads();
    }
    if (t < 512) {
        int ex = lsc[t] - lh[t];
        int node = b * 512 + t;
        if (node <= N_NODES) off[node] = base + ex;
        lh[t] = base + ex;
    }
    __syncthreads();
    for (int i = base + t; i < endv; i += 1024) {
        unsigned v = binned[i];
        int pos = atomicAdd(&lh[v >> 17], 1);
        csr[pos] = (int)(v & 0x1FFFFu);
    }
}

// ---------------- Layer 1 GEMM: 64 nodes/block, 8n x 4c register tile ----------------

__global__ __launch_bounds__(256) void gemm1_kernel(
        const float* __restrict__ x, const float* __restrict__ W1,
        const float* __restrict__ att_src1, const float* __restrict__ att_dst1,
        _Float16* __restrict__ xw1h, float* __restrict__ as1, float* __restrict__ ad1) {
    __shared__ float xt[128 * 66];          // xt[k][node], pad 2
    int tid = threadIdx.x;
    int base = blockIdx.x * 64;
#pragma unroll 4
    for (int it = 0; it < 32; ++it) {
        int e = it * 256 + tid;
        int nn = e >> 7, c = e & 127;
        float v = (base + nn < N_NODES) ? x[(size_t)base * 128 + e] : 0.f;
        xt[c * 66 + nn] = v;
    }
    __syncthreads();
    int cg = tid & 31, ng = tid >> 5;
    float acc[8][4];
#pragma unroll
    for (int i = 0; i < 8; i++)
#pragma unroll
        for (int j = 0; j < 4; j++) acc[i][j] = 0.f;

#pragma unroll 4
    for (int k = 0; k < 128; ++k) {
        float4 w = *(const float4*)&W1[k * 128 + 4 * cg];
        const float* xr = &xt[k * 66 + 8 * ng];
        float2 a0 = *(const float2*)&xr[0];
        float2 a1 = *(const float2*)&xr[2];
        float2 a2 = *(const float2*)&xr[4];
        float2 a3 = *(const float2*)&xr[6];
        float xv[8] = {a0.x, a0.y, a1.x, a1.y, a2.x, a2.y, a3.x, a3.y};
#pragma unroll
        for (int i = 0; i < 8; i++) {
            acc[i][0] = fmaf(xv[i], w.x, acc[i][0]);
            acc[i][1] = fmaf(xv[i], w.y, acc[i][1]);
            acc[i][2] = fmaf(xv[i], w.z, acc[i][2]);
            acc[i][3] = fmaf(xv[i], w.w, acc[i][3]);
        }
    }
    int c0 = 4 * cg;
    float s0 = att_src1[c0], s1 = att_src1[c0 + 1], s2 = att_src1[c0 + 2], s3 = att_src1[c0 + 3];
    float d0 = att_dst1[c0], d1 = att_dst1[c0 + 1], d2 = att_dst1[c0 + 2], d3 = att_dst1[c0 + 3];
#pragma unroll
    for (int i = 0; i < 8; i++) {
        int n = base + 8 * ng + i;
        bool ok = n < N_NODES;
        if (ok) {
            half4v hv;
            hv.x = (_Float16)acc[i][0]; hv.y = (_Float16)acc[i][1];
            hv.z = (_Float16)acc[i][2]; hv.w = (_Float16)acc[i][3];
            *(half4v*)&xw1h[(size_t)n * 128 + c0] = hv;
        }
        float ps = acc[i][0] * s0 + acc[i][1] * s1 + acc[i][2] * s2 + acc[i][3] * s3;
        float pd = acc[i][0] * d0 + acc[i][1] * d1 + acc[i][2] * d2 + acc[i][3] * d3;
#pragma unroll
        for (int m = 8; m >= 1; m >>= 1) {
            ps += __shfl_xor(ps, m);
            pd += __shfl_xor(pd, m);
        }
        if (ok && (cg == 0 || cg == 16)) {
            int hh = cg >> 4;
            as1[n * 2 + hh] = ps;
            ad1[n * 2 + hh] = pd;
        }
    }
}

// ---------------- Layer 1 aggregation: one wave per node, 2 edges/iter, fp16 gather ----

__global__ __launch_bounds__(256) void agg1_kernel(
        const int* __restrict__ off, const int* __restrict__ csr_src,
        const float* __restrict__ as1, const float* __restrict__ ad1,
        const _Float16* __restrict__ xw1h, const float* __restrict__ b1,
        float* __restrict__ h) {
    int wv = threadIdx.x >> 6, lane = threadIdx.x & 63;
    int n = blockIdx.x * 4 + wv;
    if (n >= N_NODES) return;
    int s = off[n], e = off[n + 1];
    float adn0 = ad1[2 * n], adn1 = ad1[2 * n + 1];
    int e2 = lane >> 5, q = lane & 31;      // cols 4q..4q+3; head = q>>4
    float acc0 = 0.f, acc1 = 0.f, acc2 = 0.f, acc3 = 0.f, sum0 = 0.f, sum1 = 0.f;
    for (int b = s; b < e; b += 64) {
        int cnt = min(64, e - b);
        int l = lane < cnt ? lane : cnt - 1;
        int srcv = csr_src[b + l];
        float2 a = *(const float2*)&as1[2 * srcv];
        float e0 = a.x + adn0; e0 = e0 > 0.f ? e0 : NEG_SLOPE * e0;
        float e1 = a.y + adn1; e1 = e1 > 0.f ? e1 : NEG_SLOPE * e1;
        float f0v = (lane < cnt) ? __expf(e0) : 0.f;
        float f1v = (lane < cnt) ? __expf(e1) : 0.f;
        float r0 = f0v, r1 = f1v;
#pragma unroll
        for (int m = 32; m >= 1; m >>= 1) { r0 += __shfl_xor(r0, m); r1 += __shfl_xor(r1, m); }
        sum0 += r0; sum1 += r1;
        for (int jj = 0; jj < cnt; jj += 2) {
            int j = jj + e2;
            bool val = j < cnt;
            int sl = val ? j : jj;
            int src = __shfl(srcv, sl);
            float ff0 = __shfl(f0v, sl);
            float ff1 = __shfl(f1v, sl);
            float f = (q >= 16) ? ff1 : ff0;
            if (!val) f = 0.f;
            half4v hv = *(const half4v*)&xw1h[(size_t)src * 128 + 4 * q];
            acc0 = fmaf((float)hv.x, f, acc0);
            acc1 = fmaf((float)hv.y, f, acc1);
            acc2 = fmaf((float)hv.z, f, acc2);
            acc3 = fmaf((float)hv.w, f, acc3);
        }
    }
    acc0 += __shfl_xor(acc0, 32);
    acc1 += __shfl_xor(acc1, 32);
    acc2 += __shfl_xor(acc2, 32);
    acc3 += __shfl_xor(acc3, 32);
    if (lane < 32) {
        float sum = (q >= 16) ? sum1 : sum0;
        int c = 4 * q;
        float4 bb = *(const float4*)&b1[c];
        float v0 = acc0 / sum + bb.x;
        float v1 = acc1 / sum + bb.y;
        float v2 = acc2 / sum + bb.z;
        float v3 = acc3 / sum + bb.w;
        float4 o;
        o.x = v0 > 0.f ? v0 : 0.f; o.y = v1 > 0.f ? v1 : 0.f;
        o.z = v2 > 0.f ? v2 : 0.f; o.w = v3 > 0.f ? v3 : 0.f;
        *(float4*)&h[(size_t)n * 128 + c] = o;
    }
}

// ---------------- Layer 2 GEMM: 64 nodes/block, 4n x 4c tile ----------------

__global__ __launch_bounds__(256) void gemm2_kernel(
        const float* __restrict__ h, const float* __restrict__ W2,
        const float* __restrict__ att_src2, const float* __restrict__ att_dst2,
        _Float16* __restrict__ xw2h, float* __restrict__ as2, float* __restrict__ ad2) {
    __shared__ float xt[128 * 66];
    int tid = threadIdx.x;
    int base = blockIdx.x * 64;
#pragma unroll 4
    for (int it = 0; it < 32; ++it) {
        int e = it * 256 + tid;
        int nn = e >> 7, c = e & 127;
        float v = (base + nn < N_NODES) ? h[(size_t)base * 128 + e] : 0.f;
        xt[c * 66 + nn] = v;
    }
    __syncthreads();
    int cg = tid & 15, ng = tid >> 4;
    float acc[4][4];
#pragma unroll
    for (int i = 0; i < 4; i++)
#pragma unroll
        for (int j = 0; j < 4; j++) acc[i][j] = 0.f;

#pragma unroll 4
    for (int k = 0; k < 128; ++k) {
        float4 w = *(const float4*)&W2[k * 64 + 4 * cg];
        const float* xr = &xt[k * 66 + 4 * ng];
        float2 a0 = *(const float2*)&xr[0];
        float2 a1 = *(const float2*)&xr[2];
        float xv[4] = {a0.x, a0.y, a1.x, a1.y};
#pragma unroll
        for (int i = 0; i < 4; i++) {
            acc[i][0] = fmaf(xv[i], w.x, acc[i][0]);
            acc[i][1] = fmaf(xv[i], w.y, acc[i][1]);
            acc[i][2] = fmaf(xv[i], w.z, acc[i][2]);
            acc[i][3] = fmaf(xv[i], w.w, acc[i][3]);
        }
    }
    int c0 = 4 * cg;
    float s0 = att_src2[c0], s1 = att_src2[c0 + 1], s2 = att_src2[c0 + 2], s3 = att_src2[c0 + 3];
    float d0 = att_dst2[c0], d1 = att_dst2[c0 + 1], d2 = att_dst2[c0 + 2], d3 = att_dst2[c0 + 3];
#pragma unroll
    for (int i = 0; i < 4; i++) {
        int n = base + 4 * ng + i;
        bool ok = n < N_NODES;
        if (ok) {
            half4v hv;
            hv.x = (_Float16)acc[i][0]; hv.y = (_Float16)acc[i][1];
            hv.z = (_Float16)acc[i][2]; hv.w = (_Float16)acc[i][3];
            *(half4v*)&xw2h[(size_t)n * 64 + c0] = hv;
        }
        float ps = acc[i][0] * s0 + acc[i][1] * s1 + acc[i][2] * s2 + acc[i][3] * s3;
        float pd = acc[i][0] * d0 + acc[i][1] * d1 + acc[i][2] * d2 + acc[i][3] * d3;
#pragma unroll
        for (int m = 8; m >= 1; m >>= 1) {
            ps += __shfl_xor(ps, m);
            pd += __shfl_xor(pd, m);
        }
        if (ok && cg == 0) { as2[n] = ps; ad2[n] = pd; }
    }
}

// ---------------- Layer 2 aggregation: 4 edges/iter, fp16 gather ----------------

__global__ __launch_bounds__(256) void agg2_kernel(
        const int* __restrict__ off, const int* __restrict__ csr_src,
        const float* __restrict__ as2, const float* __restrict__ ad2,
        const _Float16* __restrict__ xw2h, const float* __restrict__ b2,
        float* __restrict__ z) {
    int wv = threadIdx.x >> 6, lane = threadIdx.x & 63;
    int n = blockIdx.x * 4 + wv;
    if (n >= N_NODES) return;
    int s = off[n], e = off[n + 1];
    float adn = ad2[n];
    int e4 = lane >> 4, q = lane & 15;      // cols 4q..4q+3
    float acc0 = 0.f, acc1 = 0.f, acc2 = 0.f, acc3 = 0.f, sum = 0.f;
    for (int b = s; b < e; b += 64) {
        int cnt = min(64, e - b);
        int l = lane < cnt ? lane : cnt - 1;
        int srcv = csr_src[b + l];
        float a = as2[srcv];
        float ev = a + adn; ev = ev > 0.f ? ev : NEG_SLOPE * ev;
        float fv = (lane < cnt) ? __expf(ev) : 0.f;
        float r = fv;
#pragma unroll
        for (int m = 32; m >= 1; m >>= 1) r += __shfl_xor(r, m);
        sum += r;
        for (int jj = 0; jj < cnt; jj += 4) {
            int j = jj + e4;
            bool val = j < cnt;
            int sl = val ? j : jj;
            int src = __shfl(srcv, sl);
            float f = __shfl(fv, sl);
            if (!val) f = 0.f;
            half4v hv = *(const half4v*)&xw2h[(size_t)src * 64 + 4 * q];
            acc0 = fmaf((float)hv.x, f, acc0);
            acc1 = fmaf((float)hv.y, f, acc1);
            acc2 = fmaf((float)hv.z, f, acc2);
            acc3 = fmaf((float)hv.w, f, acc3);
        }
    }
#pragma unroll
    for (int m = 32; m >= 16; m >>= 1) {
        acc0 += __shfl_xor(acc0, m);
        acc1 += __shfl_xor(acc1, m);
        acc2 += __shfl_xor(acc2, m);
        acc3 += __shfl_xor(acc3, m);
    }
    if (lane < 16) {
        int c = 4 * q;
        float4 bb = *(const float4*)&b2[c];
        float4 o;
        o.x = acc0 / sum + bb.x;
        o.y = acc1 / sum + bb.y;
        o.z = acc2 / sum + bb.z;
        o.w = acc3 / sum + bb.w;
        *(float4*)&z[(size_t)n * 64 + c] = o;
    }
}

// ---------------- Link decode ----------------

__global__ __launch_bounds__(256) void decode_kernel(
        const int* __restrict__ pos_ei, const int* __restrict__ neg_ei,
        const float* __restrict__ z, const float* __restrict__ lw,
        const float* __restrict__ lb, float* __restrict__ out) {
    int wv = threadIdx.x >> 6, lane = threadIdx.x & 63;
    int idx = blockIdx.x * 4 + wv;
    if (idx >= 2 * P_CAND) return;
    const int* ei; int p;
    if (idx < P_CAND) { ei = pos_ei; p = idx; }
    else              { ei = neg_ei; p = idx - P_CAND; }
    int sN = ei[p], dN = ei[P_CAND + p];
    float2 zz, ww;
    if (lane < 32) {
        zz = *(const float2*)&z[(size_t)sN * 64 + 2 * lane];
        ww = *(const float2*)&lw[2 * lane];
    } else {
        int q = lane - 32;
        zz = *(const float2*)&z[(size_t)dN * 64 + 2 * q];
        ww = *(const float2*)&lw[64 + 2 * q];
    }
    float v = zz.x * ww.x + zz.y * ww.y;
#pragma unroll
    for (int m = 32; m >= 1; m >>= 1) v += __shfl_xor(v, m);
    if (lane == 0) out[idx] = v + lb[0];
}

// ---------------- launch ----------------

extern "C" void kernel_launch(void* const* d_in, const int* in_sizes, int n_in,
                              void* d_out, int out_size, void* d_ws, size_t ws_size,
                              hipStream_t stream) {
    const float* x        = (const float*)d_in[0];
    const int*   ei       = (const int*)d_in[1];
    const int*   pos_ei   = (const int*)d_in[3];
    const int*   neg_ei   = (const int*)d_in[4];
    const float* W1       = (const float*)d_in[5];
    const float* att_src1 = (const float*)d_in[6];
    const float* att_dst1 = (const float*)d_in[7];
    const float* b1       = (const float*)d_in[8];
    const float* W2       = (const float*)d_in[9];
    const float* att_src2 = (const float*)d_in[10];
    const float* att_dst2 = (const float*)d_in[11];
    const float* b2       = (const float*)d_in[12];
    const float* lw       = (const float*)d_in[13];
    const float* lb       = (const float*)d_in[14];
    float* out = (float*)d_out;

    char* ws = (char*)d_ws;
    size_t o = 0;
    auto alloc = [&](size_t bytes) -> char* {
        char* p = ws + o;
        o += (bytes + 511) & ~(size_t)511;
        return p;
    };
    _Float16* xw1h  = (_Float16*)alloc((size_t)N_NODES * 128 * 2);  // reused: xw2h
    float*    h     = (float*)alloc((size_t)N_NODES * 128 * 4);
    float*    z     = (float*)alloc((size_t)N_NODES * 64 * 4);
    float*    as1   = (float*)alloc((size_t)N_NODES * 2 * 4);
    float*    ad1   = (float*)alloc((size_t)N_NODES * 2 * 4);
    float*    as2   = (float*)alloc((size_t)N_NODES * 4);
    float*    ad2   = (float*)alloc((size_t)N_NODES * 4);
    int*      off   = (int*)alloc((size_t)(N_NODES + 1) * 4);
    int*      hist  = (int*)alloc((size_t)NTOT * 4);
    int*      histS = (int*)alloc((size_t)NTOT * 4);
    unsigned* binned= (unsigned*)alloc((size_t)EP * 4);
    int*      csr   = (int*)alloc((size_t)EP * 4);
    _Float16* xw2h  = xw1h;    // xw1h dead after agg1

    hist_kernel<<<NB2, 256, 0, stream>>>(ei, hist);
    scan2_kernel<<<1, 1024, 0, stream>>>(hist, histS);
    scatterbin_kernel<<<NB2, 256, 0, stream>>>(ei, histS, binned);
    binsort_kernel<<<NBIN, 1024, 0, stream>>>(binned, histS, off, csr);
    gemm1_kernel<<<(N_NODES + 63) / 64, 256, 0, stream>>>(x, W1, att_src1, att_dst1, xw1h, as1, ad1);
    agg1_kernel<<<(N_NODES + 3) / 4, 256, 0, stream>>>(off, csr, as1, ad1, xw1h, b1, h);
    gemm2_kernel<<<(N_NODES + 63) / 64, 256, 0, stream>>>(h, W2, att_src2, att_dst2, xw2h, as2, ad2);
    agg2_kernel<<<(N_NODES + 3) / 4, 256, 0, stream>>>(off, csr, as2, ad2, xw2h, b2, z);
    decode_kernel<<<(2 * P_CAND + 3) / 4, 256, 0, stream>>>(pos_ei, neg_ei, z, lw, lb, out);
}

// Round 7
// 456.186 us; speedup vs baseline: 2.8432x; 1.2442x over previous
//
#include <hip/hip_runtime.h>

#define N_NODES 100000
#define E_EDGES 1600000
#define EP      (E_EDGES + N_NODES)   // edges + self loops = 1,700,000
#define P_CAND  262144
#define IN_C    128
#define HID     64
#define NEG_SLOPE 0.2f

#define NBIN  196            // ceil(100000/512) bins of 512 nodes
#define NB2   256            // blocks for hist/scatterbin
#define EPB   ((EP + NB2 - 1) / NB2)   // 6641 edges per block
#define NTOT  (NBIN * NB2)   // 50176 (= 1024*49)

typedef _Float16 half4v __attribute__((ext_vector_type(4)));

// ---------------- CSR build: deterministic 2-level counting sort ----------------

__global__ __launch_bounds__(256) void hist_kernel(const int* __restrict__ ei,
                                                   int* __restrict__ hist) {
    __shared__ int lh[NBIN];
    for (int t = threadIdx.x; t < NBIN; t += 256) lh[t] = 0;
    __syncthreads();
    int start = blockIdx.x * EPB;
    int end = min(start + EPB, EP);
    for (int i = start + threadIdx.x; i < end; i += 256) {
        int dst = (i < E_EDGES) ? ei[E_EDGES + i] : (i - E_EDGES);
        atomicAdd(&lh[dst >> 9], 1);
    }
    __syncthreads();
    for (int t = threadIdx.x; t < NBIN; t += 256) hist[t * NB2 + blockIdx.x] = lh[t];
}

__global__ __launch_bounds__(1024) void scan2_kernel(const int* __restrict__ hist,
                                                     int* __restrict__ histS) {
    __shared__ int s[1024];
    int t = threadIdx.x;
    int b0 = t * 49;                       // 1024*49 == 50176
    int sum = 0;
    for (int i = 0; i < 49; i++) sum += hist[b0 + i];
    s[t] = sum;
    __syncthreads();
    for (int d = 1; d < 1024; d <<= 1) {
        int v = (t >= d) ? s[t - d] : 0;
        __syncthreads();
        s[t] += v;
        __syncthreads();
    }
    int run = s[t] - sum;
    for (int i = 0; i < 49; i++) { int hv = hist[b0 + i]; histS[b0 + i] = run; run += hv; }
}

__global__ __launch_bounds__(256) void scatterbin_kernel(const int* __restrict__ ei,
                                                         const int* __restrict__ histS,
                                                         unsigned* __restrict__ binned) {
    __shared__ int cur[NBIN];
    for (int t = threadIdx.x; t < NBIN; t += 256) cur[t] = histS[t * NB2 + blockIdx.x];
    __syncthreads();
    int start = blockIdx.x * EPB;
    int end = min(start + EPB, EP);
    for (int i = start + threadIdx.x; i < end; i += 256) {
        int src, dst;
        if (i < E_EDGES) { src = ei[i]; dst = ei[E_EDGES + i]; }
        else             { src = i - E_EDGES; dst = src; }
        int pos = atomicAdd(&cur[dst >> 9], 1);
        binned[pos] = (unsigned)src | ((unsigned)(dst & 511) << 17);
    }
}

__global__ __launch_bounds__(1024) void binsort_kernel(const unsigned* __restrict__ binned,
                                                       const int* __restrict__ histS,
                                                       int* __restrict__ off,
                                                       int* __restrict__ csr) {
    __shared__ int lh[512];
    __shared__ int lsc[512];
    int b = blockIdx.x, t = threadIdx.x;
    int base = histS[b * NB2];
    int endv = (b == NBIN - 1) ? EP : histS[(b + 1) * NB2];
    if (t < 512) lh[t] = 0;
    __syncthreads();
    for (int i = base + t; i < endv; i += 1024)
        atomicAdd(&lh[binned[i] >> 17], 1);
    __syncthreads();
    if (t < 512) lsc[t] = lh[t];
    __syncthreads();
    for (int d = 1; d < 512; d <<= 1) {
        int v = (t >= d && t < 512) ? lsc[t - d] : 0;
        __syncthreads();
        if (t < 512) lsc[t] += v;
        __syncthreads();
    }
    if (t < 512) {
        int ex = lsc[t] - lh[t];
        int node = b * 512 + t;
        if (node <= N_NODES) off[node] = base + ex;
        lh[t] = base + ex;
    }
    __syncthreads();
    for (int i = base + t; i < endv; i += 1024) {
        unsigned v = binned[i];
        int pos = atomicAdd(&lh[v >> 17], 1);
        csr[pos] = (int)(v & 0x1FFFFu);
    }
}

// ---------------- Layer 1 GEMM: 64 nodes/block, 8n x 4c register tile ----------------

__global__ __launch_bounds__(256) void gemm1_kernel(
        const float* __restrict__ x, const float* __restrict__ W1,
        const float* __restrict__ att_src1, const float* __restrict__ att_dst1,
        _Float16* __restrict__ xw1h, float* __restrict__ as1, float* __restrict__ ad1) {
    __shared__ float xt[128 * 66];          // xt[k][node], pad 2
    int tid = threadIdx.x;
    int base = blockIdx.x * 64;
#pragma unroll 4
    for (int it = 0; it < 32; ++it) {
        int e = it * 256 + tid;
        int nn = e >> 7, c = e & 127;
        float v = (base + nn < N_NODES) ? x[(size_t)base * 128 + e] : 0.f;
        xt[c * 66 + nn] = v;
    }
    __syncthreads();
    int cg = tid & 31, ng = tid >> 5;
    float acc[8][4];
#pragma unroll
    for (int i = 0; i < 8; i++)
#pragma unroll
        for (int j = 0; j < 4; j++) acc[i][j] = 0.f;

#pragma unroll 4
    for (int k = 0; k < 128; ++k) {
        float4 w = *(const float4*)&W1[k * 128 + 4 * cg];
        const float* xr = &xt[k * 66 + 8 * ng];
        float2 a0 = *(const float2*)&xr[0];
        float2 a1 = *(const float2*)&xr[2];
        float2 a2 = *(const float2*)&xr[4];
        float2 a3 = *(const float2*)&xr[6];
        float xv[8] = {a0.x, a0.y, a1.x, a1.y, a2.x, a2.y, a3.x, a3.y};
#pragma unroll
        for (int i = 0; i < 8; i++) {
            acc[i][0] = fmaf(xv[i], w.x, acc[i][0]);
            acc[i][1] = fmaf(xv[i], w.y, acc[i][1]);
            acc[i][2] = fmaf(xv[i], w.z, acc[i][2]);
            acc[i][3] = fmaf(xv[i], w.w, acc[i][3]);
        }
    }
    int c0 = 4 * cg;
    float s0 = att_src1[c0], s1 = att_src1[c0 + 1], s2 = att_src1[c0 + 2], s3 = att_src1[c0 + 3];
    float d0 = att_dst1[c0], d1 = att_dst1[c0 + 1], d2 = att_dst1[c0 + 2], d3 = att_dst1[c0 + 3];
#pragma unroll
    for (int i = 0; i < 8; i++) {
        int n = base + 8 * ng + i;
        bool ok = n < N_NODES;
        if (ok) {
            half4v hv;
            hv.x = (_Float16)acc[i][0]; hv.y = (_Float16)acc[i][1];
            hv.z = (_Float16)acc[i][2]; hv.w = (_Float16)acc[i][3];
            *(half4v*)&xw1h[(size_t)n * 128 + c0] = hv;
        }
        float ps = acc[i][0] * s0 + acc[i][1] * s1 + acc[i][2] * s2 + acc[i][3] * s3;
        float pd = acc[i][0] * d0 + acc[i][1] * d1 + acc[i][2] * d2 + acc[i][3] * d3;
#pragma unroll
        for (int m = 8; m >= 1; m >>= 1) {
            ps += __shfl_xor(ps, m);
            pd += __shfl_xor(pd, m);
        }
        if (ok && (cg == 0 || cg == 16)) {
            int hh = cg >> 4;
            as1[n * 2 + hh] = ps;
            ad1[n * 2 + hh] = pd;
        }
    }
}

// ---------------- Layer 1 aggregation: one wave per node, 2 edges/iter, fp16 gather ----

__global__ __launch_bounds__(256) void agg1_kernel(
        const int* __restrict__ off, const int* __restrict__ csr_src,
        const float* __restrict__ as1, const float* __restrict__ ad1,
        const _Float16* __restrict__ xw1h, const float* __restrict__ b1,
        float* __restrict__ h) {
    int wv = threadIdx.x >> 6, lane = threadIdx.x & 63;
    int n = blockIdx.x * 4 + wv;
    if (n >= N_NODES) return;
    int s = off[n], e = off[n + 1];
    float adn0 = ad1[2 * n], adn1 = ad1[2 * n + 1];
    int e2 = lane >> 5, q = lane & 31;      // cols 4q..4q+3; head = q>>4
    float acc0 = 0.f, acc1 = 0.f, acc2 = 0.f, acc3 = 0.f, sum0 = 0.f, sum1 = 0.f;
    for (int b = s; b < e; b += 64) {
        int cnt = min(64, e - b);
        int l = lane < cnt ? lane : cnt - 1;
        int srcv = csr_src[b + l];
        float2 a = *(const float2*)&as1[2 * srcv];
        float e0 = a.x + adn0; e0 = e0 > 0.f ? e0 : NEG_SLOPE * e0;
        float e1 = a.y + adn1; e1 = e1 > 0.f ? e1 : NEG_SLOPE * e1;
        float f0v = (lane < cnt) ? __expf(e0) : 0.f;
        float f1v = (lane < cnt) ? __expf(e1) : 0.f;
        float r0 = f0v, r1 = f1v;
#pragma unroll
        for (int m = 32; m >= 1; m >>= 1) { r0 += __shfl_xor(r0, m); r1 += __shfl_xor(r1, m); }
        sum0 += r0; sum1 += r1;
        for (int jj = 0; jj < cnt; jj += 2) {
            int j = jj + e2;
            bool val = j < cnt;
            int sl = val ? j : jj;
            int src = __shfl(srcv, sl);
            float ff0 = __shfl(f0v, sl);
            float ff1 = __shfl(f1v, sl);
            float f = (q >= 16) ? ff1 : ff0;
            if (!val) f = 0.f;
            half4v hv = *(const half4v*)&xw1h[(size_t)src * 128 + 4 * q];
            acc0 = fmaf((float)hv.x, f, acc0);
            acc1 = fmaf((float)hv.y, f, acc1);
            acc2 = fmaf((float)hv.z, f, acc2);
            acc3 = fmaf((float)hv.w, f, acc3);
        }
    }
    acc0 += __shfl_xor(acc0, 32);
    acc1 += __shfl_xor(acc1, 32);
    acc2 += __shfl_xor(acc2, 32);
    acc3 += __shfl_xor(acc3, 32);
    if (lane < 32) {
        float sum = (q >= 16) ? sum1 : sum0;
        int c = 4 * q;
        float4 bb = *(const float4*)&b1[c];
        float v0 = acc0 / sum + bb.x;
        float v1 = acc1 / sum + bb.y;
        float v2 = acc2 / sum + bb.z;
        float v3 = acc3 / sum + bb.w;
        float4 o;
        o.x = v0 > 0.f ? v0 : 0.f; o.y = v1 > 0.f ? v1 : 0.f;
        o.z = v2 > 0.f ? v2 : 0.f; o.w = v3 > 0.f ? v3 : 0.f;
        *(float4*)&h[(size_t)n * 128 + c] = o;
    }
}

// ---------------- Layer 2 GEMM: 64 nodes/block, 4n x 4c tile ----------------

__global__ __launch_bounds__(256) void gemm2_kernel(
        const float* __restrict__ h, const float* __restrict__ W2,
        const float* __restrict__ att_src2, const float* __restrict__ att_dst2,
        _Float16* __restrict__ xw2h, float* __restrict__ as2, float* __restrict__ ad2) {
    __shared__ float xt[128 * 66];
    int tid = threadIdx.x;
    int base = blockIdx.x * 64;
#pragma unroll 4
    for (int it = 0; it < 32; ++it) {
        int e = it * 256 + tid;
        int nn = e >> 7, c = e & 127;
        float v = (base + nn < N_NODES) ? h[(size_t)base * 128 + e] : 0.f;
        xt[c * 66 + nn] = v;
    }
    __syncthreads();
    int cg = tid & 15, ng = tid >> 4;
    float acc[4][4];
#pragma unroll
    for (int i = 0; i < 4; i++)
#pragma unroll
        for (int j = 0; j < 4; j++) acc[i][j] = 0.f;

#pragma unroll 4
    for (int k = 0; k < 128; ++k) {
        float4 w = *(const float4*)&W2[k * 64 + 4 * cg];
        const float* xr = &xt[k * 66 + 4 * ng];
        float2 a0 = *(const float2*)&xr[0];
        float2 a1 = *(const float2*)&xr[2];
        float xv[4] = {a0.x, a0.y, a1.x, a1.y};
#pragma unroll
        for (int i = 0; i < 4; i++) {
            acc[i][0] = fmaf(xv[i], w.x, acc[i][0]);
            acc[i][1] = fmaf(xv[i], w.y, acc[i][1]);
            acc[i][2] = fmaf(xv[i], w.z, acc[i][2]);
            acc[i][3] = fmaf(xv[i], w.w, acc[i][3]);
        }
    }
    int c0 = 4 * cg;
    float s0 = att_src2[c0], s1 = att_src2[c0 + 1], s2 = att_src2[c0 + 2], s3 = att_src2[c0 + 3];
    float d0 = att_dst2[c0], d1 = att_dst2[c0 + 1], d2 = att_dst2[c0 + 2], d3 = att_dst2[c0 + 3];
#pragma unroll
    for (int i = 0; i < 4; i++) {
        int n = base + 4 * ng + i;
        bool ok = n < N_NODES;
        if (ok) {
            half4v hv;
            hv.x = (_Float16)acc[i][0]; hv.y = (_Float16)acc[i][1];
            hv.z = (_Float16)acc[i][2]; hv.w = (_Float16)acc[i][3];
            *(half4v*)&xw2h[(size_t)n * 64 + c0] = hv;
        }
        float ps = acc[i][0] * s0 + acc[i][1] * s1 + acc[i][2] * s2 + acc[i][3] * s3;
        float pd = acc[i][0] * d0 + acc[i][1] * d1 + acc[i][2] * d2 + acc[i][3] * d3;
#pragma unroll
        for (int m = 8; m >= 1; m >>= 1) {
            ps += __shfl_xor(ps, m);
            pd += __shfl_xor(pd, m);
        }
        if (ok && cg == 0) { as2[n] = ps; ad2[n] = pd; }
    }
}

// ---------------- Layer 2 aggregation: 4 edges/iter, fp16 gather, fused u/v epilogue ----

__global__ __launch_bounds__(256) void agg2_kernel(
        const int* __restrict__ off, const int* __restrict__ csr_src,
        const float* __restrict__ as2, const float* __restrict__ ad2,
        const _Float16* __restrict__ xw2h, const float* __restrict__ b2,
        const float* __restrict__ lw, float* __restrict__ u, float* __restrict__ v) {
    int wv = threadIdx.x >> 6, lane = threadIdx.x & 63;
    int n = blockIdx.x * 4 + wv;
    if (n >= N_NODES) return;
    int s = off[n], e = off[n + 1];
    float adn = ad2[n];
    int e4 = lane >> 4, q = lane & 15;      // cols 4q..4q+3
    float acc0 = 0.f, acc1 = 0.f, acc2 = 0.f, acc3 = 0.f, sum = 0.f;
    for (int b = s; b < e; b += 64) {
        int cnt = min(64, e - b);
        int l = lane < cnt ? lane : cnt - 1;
        int srcv = csr_src[b + l];
        float a = as2[srcv];
        float ev = a + adn; ev = ev > 0.f ? ev : NEG_SLOPE * ev;
        float fv = (lane < cnt) ? __expf(ev) : 0.f;
        float r = fv;
#pragma unroll
        for (int m = 32; m >= 1; m >>= 1) r += __shfl_xor(r, m);
        sum += r;
        for (int jj = 0; jj < cnt; jj += 4) {
            int j = jj + e4;
            bool val = j < cnt;
            int sl = val ? j : jj;
            int src = __shfl(srcv, sl);
            float f = __shfl(fv, sl);
            if (!val) f = 0.f;
            half4v hv = *(const half4v*)&xw2h[(size_t)src * 64 + 4 * q];
            acc0 = fmaf((float)hv.x, f, acc0);
            acc1 = fmaf((float)hv.y, f, acc1);
            acc2 = fmaf((float)hv.z, f, acc2);
            acc3 = fmaf((float)hv.w, f, acc3);
        }
    }
#pragma unroll
    for (int m = 32; m >= 16; m >>= 1) {
        acc0 += __shfl_xor(acc0, m);
        acc1 += __shfl_xor(acc1, m);
        acc2 += __shfl_xor(acc2, m);
        acc3 += __shfl_xor(acc3, m);
    }
    // lanes 0..15 hold the final z row (cols 4q..4q+3); fuse link-pred dots
    int c = 4 * q;
    float4 bb = *(const float4*)&b2[c];
    float z0 = acc0 / sum + bb.x;
    float z1 = acc1 / sum + bb.y;
    float z2 = acc2 / sum + bb.z;
    float z3 = acc3 / sum + bb.w;
    float4 wu = *(const float4*)&lw[c];
    float4 wv4 = *(const float4*)&lw[64 + c];
    float pu = z0 * wu.x + z1 * wu.y + z2 * wu.z + z3 * wu.w;
    float pv = z0 * wv4.x + z1 * wv4.y + z2 * wv4.z + z3 * wv4.w;
#pragma unroll
    for (int m = 8; m >= 1; m >>= 1) {
        pu += __shfl_xor(pu, m);
        pv += __shfl_xor(pv, m);
    }
    if (lane == 0) { u[n] = pu; v[n] = pv; }
}

// ---------------- Link decode: out = u[s] + v[d] + lb, one thread per candidate ------

__global__ __launch_bounds__(256) void decode_kernel(
        const int* __restrict__ pos_ei, const int* __restrict__ neg_ei,
        const float* __restrict__ u, const float* __restrict__ v,
        const float* __restrict__ lb, float* __restrict__ out) {
    int idx = blockIdx.x * 256 + threadIdx.x;
    if (idx >= 2 * P_CAND) return;
    const int* ei; int p;
    if (idx < P_CAND) { ei = pos_ei; p = idx; }
    else              { ei = neg_ei; p = idx - P_CAND; }
    int sN = ei[p], dN = ei[P_CAND + p];
    out[idx] = u[sN] + v[dN] + lb[0];
}

// ---------------- launch ----------------

extern "C" void kernel_launch(void* const* d_in, const int* in_sizes, int n_in,
                              void* d_out, int out_size, void* d_ws, size_t ws_size,
                              hipStream_t stream) {
    const float* x        = (const float*)d_in[0];
    const int*   ei       = (const int*)d_in[1];
    const int*   pos_ei   = (const int*)d_in[3];
    const int*   neg_ei   = (const int*)d_in[4];
    const float* W1       = (const float*)d_in[5];
    const float* att_src1 = (const float*)d_in[6];
    const float* att_dst1 = (const float*)d_in[7];
    const float* b1       = (const float*)d_in[8];
    const float* W2       = (const float*)d_in[9];
    const float* att_src2 = (const float*)d_in[10];
    const float* att_dst2 = (const float*)d_in[11];
    const float* b2       = (const float*)d_in[12];
    const float* lw       = (const float*)d_in[13];
    const float* lb       = (const float*)d_in[14];
    float* out = (float*)d_out;

    char* ws = (char*)d_ws;
    size_t o = 0;
    auto alloc = [&](size_t bytes) -> char* {
        char* p = ws + o;
        o += (bytes + 511) & ~(size_t)511;
        return p;
    };
    _Float16* xw1h  = (_Float16*)alloc((size_t)N_NODES * 128 * 2);  // reused: xw2h
    float*    h     = (float*)alloc((size_t)N_NODES * 128 * 4);
    float*    u     = (float*)alloc((size_t)N_NODES * 4);
    float*    v     = (float*)alloc((size_t)N_NODES * 4);
    float*    as1   = (float*)alloc((size_t)N_NODES * 2 * 4);
    float*    ad1   = (float*)alloc((size_t)N_NODES * 2 * 4);
    float*    as2   = (float*)alloc((size_t)N_NODES * 4);
    float*    ad2   = (float*)alloc((size_t)N_NODES * 4);
    int*      off   = (int*)alloc((size_t)(N_NODES + 1) * 4);
    int*      hist  = (int*)alloc((size_t)NTOT * 4);
    int*      histS = (int*)alloc((size_t)NTOT * 4);
    unsigned* binned= (unsigned*)alloc((size_t)EP * 4);
    int*      csr   = (int*)alloc((size_t)EP * 4);
    _Float16* xw2h  = xw1h;    // xw1h dead after agg1

    hist_kernel<<<NB2, 256, 0, stream>>>(ei, hist);
    scan2_kernel<<<1, 1024, 0, stream>>>(hist, histS);
    scatterbin_kernel<<<NB2, 256, 0, stream>>>(ei, histS, binned);
    binsort_kernel<<<NBIN, 1024, 0, stream>>>(binned, histS, off, csr);
    gemm1_kernel<<<(N_NODES + 63) / 64, 256, 0, stream>>>(x, W1, att_src1, att_dst1, xw1h, as1, ad1);
    agg1_kernel<<<(N_NODES + 3) / 4, 256, 0, stream>>>(off, csr, as1, ad1, xw1h, b1, h);
    gemm2_kernel<<<(N_NODES + 63) / 64, 256, 0, stream>>>(h, W2, att_src2, att_dst2, xw2h, as2, ad2);
    agg2_kernel<<<(N_NODES + 3) / 4, 256, 0, stream>>>(off, csr, as2, ad2, xw2h, b2, lw, u, v);
    decode_kernel<<<(2 * P_CAND + 255) / 256, 256, 0, stream>>>(pos_ei, neg_ei, u, v, lb, out);
}

// Round 8
// 439.454 us; speedup vs baseline: 2.9515x; 1.0381x over previous
//
#include <hip/hip_runtime.h>

#define N_NODES 100000
#define E_EDGES 1600000
#define EP      (E_EDGES + N_NODES)   // edges + self loops = 1,700,000
#define P_CAND  262144
#define IN_C    128
#define HID     64
#define NEG_SLOPE 0.2f

#define NBIN  196            // ceil(100000/512) bins of 512 nodes
#define NB2   256            // blocks for hist/scatterbin
#define EPB   ((EP + NB2 - 1) / NB2)   // 6641 edges per block
#define NTOT  (NBIN * NB2)   // 50176 (= 1024*49)

typedef _Float16 half4v __attribute__((ext_vector_type(4)));
typedef _Float16 half8v __attribute__((ext_vector_type(8)));

// ---------------- CSR build: deterministic 2-level counting sort ----------------

__global__ __launch_bounds__(256) void hist_kernel(const int* __restrict__ ei,
                                                   int* __restrict__ hist) {
    __shared__ int lh[NBIN];
    for (int t = threadIdx.x; t < NBIN; t += 256) lh[t] = 0;
    __syncthreads();
    int start = blockIdx.x * EPB;
    int end = min(start + EPB, EP);
    for (int i = start + threadIdx.x; i < end; i += 256) {
        int dst = (i < E_EDGES) ? ei[E_EDGES + i] : (i - E_EDGES);
        atomicAdd(&lh[dst >> 9], 1);
    }
    __syncthreads();
    for (int t = threadIdx.x; t < NBIN; t += 256) hist[t * NB2 + blockIdx.x] = lh[t];
}

__global__ __launch_bounds__(1024) void scan2_kernel(const int* __restrict__ hist,
                                                     int* __restrict__ histS) {
    __shared__ int s[1024];
    int t = threadIdx.x;
    int b0 = t * 49;                       // 1024*49 == 50176
    int sum = 0;
    for (int i = 0; i < 49; i++) sum += hist[b0 + i];
    s[t] = sum;
    __syncthreads();
    for (int d = 1; d < 1024; d <<= 1) {
        int v = (t >= d) ? s[t - d] : 0;
        __syncthreads();
        s[t] += v;
        __syncthreads();
    }
    int run = s[t] - sum;
    for (int i = 0; i < 49; i++) { int hv = hist[b0 + i]; histS[b0 + i] = run; run += hv; }
}

__global__ __launch_bounds__(256) void scatterbin_kernel(const int* __restrict__ ei,
                                                         const int* __restrict__ histS,
                                                         unsigned* __restrict__ binned) {
    __shared__ int cur[NBIN];
    for (int t = threadIdx.x; t < NBIN; t += 256) cur[t] = histS[t * NB2 + blockIdx.x];
    __syncthreads();
    int start = blockIdx.x * EPB;
    int end = min(start + EPB, EP);
    for (int i = start + threadIdx.x; i < end; i += 256) {
        int src, dst;
        if (i < E_EDGES) { src = ei[i]; dst = ei[E_EDGES + i]; }
        else             { src = i - E_EDGES; dst = src; }
        int pos = atomicAdd(&cur[dst >> 9], 1);
        binned[pos] = (unsigned)src | ((unsigned)(dst & 511) << 17);
    }
}

__global__ __launch_bounds__(1024) void binsort_kernel(const unsigned* __restrict__ binned,
                                                       const int* __restrict__ histS,
                                                       int* __restrict__ off,
                                                       int* __restrict__ csr) {
    __shared__ int lh[512];
    __shared__ int lsc[512];
    int b = blockIdx.x, t = threadIdx.x;
    int base = histS[b * NB2];
    int endv = (b == NBIN - 1) ? EP : histS[(b + 1) * NB2];
    if (t < 512) lh[t] = 0;
    __syncthreads();
    for (int i = base + t; i < endv; i += 1024)
        atomicAdd(&lh[binned[i] >> 17], 1);
    __syncthreads();
    if (t < 512) lsc[t] = lh[t];
    __syncthreads();
    for (int d = 1; d < 512; d <<= 1) {
        int v = (t >= d && t < 512) ? lsc[t - d] : 0;
        __syncthreads();
        if (t < 512) lsc[t] += v;
        __syncthreads();
    }
    if (t < 512) {
        int ex = lsc[t] - lh[t];
        int node = b * 512 + t;
        if (node <= N_NODES) off[node] = base + ex;
        lh[t] = base + ex;
    }
    __syncthreads();
    for (int i = base + t; i < endv; i += 1024) {
        unsigned v = binned[i];
        int pos = atomicAdd(&lh[v >> 17], 1);
        csr[pos] = (int)(v & 0x1FFFFu);
    }
}

// ---------------- Layer 1 GEMM: 64 nodes/block, 8n x 4c register tile ----------------

__global__ __launch_bounds__(256) void gemm1_kernel(
        const float* __restrict__ x, const float* __restrict__ W1,
        const float* __restrict__ att_src1, const float* __restrict__ att_dst1,
        _Float16* __restrict__ xw1h, float* __restrict__ as1, float* __restrict__ ad1) {
    __shared__ float xt[128 * 66];          // xt[k][node], pad 2
    int tid = threadIdx.x;
    int base = blockIdx.x * 64;
#pragma unroll 4
    for (int it = 0; it < 32; ++it) {
        int e = it * 256 + tid;
        int nn = e >> 7, c = e & 127;
        float v = (base + nn < N_NODES) ? x[(size_t)base * 128 + e] : 0.f;
        xt[c * 66 + nn] = v;
    }
    __syncthreads();
    int cg = tid & 31, ng = tid >> 5;
    float acc[8][4];
#pragma unroll
    for (int i = 0; i < 8; i++)
#pragma unroll
        for (int j = 0; j < 4; j++) acc[i][j] = 0.f;

#pragma unroll 4
    for (int k = 0; k < 128; ++k) {
        float4 w = *(const float4*)&W1[k * 128 + 4 * cg];
        const float* xr = &xt[k * 66 + 8 * ng];
        float2 a0 = *(const float2*)&xr[0];
        float2 a1 = *(const float2*)&xr[2];
        float2 a2 = *(const float2*)&xr[4];
        float2 a3 = *(const float2*)&xr[6];
        float xv[8] = {a0.x, a0.y, a1.x, a1.y, a2.x, a2.y, a3.x, a3.y};
#pragma unroll
        for (int i = 0; i < 8; i++) {
            acc[i][0] = fmaf(xv[i], w.x, acc[i][0]);
            acc[i][1] = fmaf(xv[i], w.y, acc[i][1]);
            acc[i][2] = fmaf(xv[i], w.z, acc[i][2]);
            acc[i][3] = fmaf(xv[i], w.w, acc[i][3]);
        }
    }
    int c0 = 4 * cg;
    float s0 = att_src1[c0], s1 = att_src1[c0 + 1], s2 = att_src1[c0 + 2], s3 = att_src1[c0 + 3];
    float d0 = att_dst1[c0], d1 = att_dst1[c0 + 1], d2 = att_dst1[c0 + 2], d3 = att_dst1[c0 + 3];
#pragma unroll
    for (int i = 0; i < 8; i++) {
        int n = base + 8 * ng + i;
        bool ok = n < N_NODES;
        if (ok) {
            half4v hv;
            hv.x = (_Float16)acc[i][0]; hv.y = (_Float16)acc[i][1];
            hv.z = (_Float16)acc[i][2]; hv.w = (_Float16)acc[i][3];
            *(half4v*)&xw1h[(size_t)n * 128 + c0] = hv;
        }
        float ps = acc[i][0] * s0 + acc[i][1] * s1 + acc[i][2] * s2 + acc[i][3] * s3;
        float pd = acc[i][0] * d0 + acc[i][1] * d1 + acc[i][2] * d2 + acc[i][3] * d3;
#pragma unroll
        for (int m = 8; m >= 1; m >>= 1) {
            ps += __shfl_xor(ps, m);
            pd += __shfl_xor(pd, m);
        }
        if (ok && (cg == 0 || cg == 16)) {
            int hh = cg >> 4;
            as1[n * 2 + hh] = ps;
            ad1[n * 2 + hh] = pd;
        }
    }
}

// ---- Layer 1 aggregation: one wave per node, 4 edges/iter, half8 (16B) gathers ----

__global__ __launch_bounds__(256) void agg1_kernel(
        const int* __restrict__ off, const int* __restrict__ csr_src,
        const float* __restrict__ as1, const float* __restrict__ ad1,
        const _Float16* __restrict__ xw1h, const float* __restrict__ b1,
        float* __restrict__ h) {
    int wv = threadIdx.x >> 6, lane = threadIdx.x & 63;
    int n = blockIdx.x * 4 + wv;
    if (n >= N_NODES) return;
    int s = off[n], e = off[n + 1];
    float adn0 = ad1[2 * n], adn1 = ad1[2 * n + 1];
    int e4 = lane >> 4, q = lane & 15;      // edge slot 0..3; cols 8q..8q+7 (q<8:head0)
    float acc[8];
#pragma unroll
    for (int i = 0; i < 8; i++) acc[i] = 0.f;
    float sum0 = 0.f, sum1 = 0.f;
    for (int b = s; b < e; b += 64) {
        int cnt = min(64, e - b);
        int l = lane < cnt ? lane : cnt - 1;
        int srcv = csr_src[b + l];
        float2 a = *(const float2*)&as1[2 * srcv];
        float e0 = a.x + adn0; e0 = e0 > 0.f ? e0 : NEG_SLOPE * e0;
        float e1 = a.y + adn1; e1 = e1 > 0.f ? e1 : NEG_SLOPE * e1;
        float f0v = (lane < cnt) ? __expf(e0) : 0.f;
        float f1v = (lane < cnt) ? __expf(e1) : 0.f;
        float r0 = f0v, r1 = f1v;
#pragma unroll
        for (int m = 32; m >= 1; m >>= 1) { r0 += __shfl_xor(r0, m); r1 += __shfl_xor(r1, m); }
        sum0 += r0; sum1 += r1;
        for (int jj = 0; jj < cnt; jj += 4) {
            int j = jj + e4;
            bool val = j < cnt;
            int sl = val ? j : jj;
            int src = __shfl(srcv, sl);
            float ff0 = __shfl(f0v, sl);
            float ff1 = __shfl(f1v, sl);
            float f = (q >= 8) ? ff1 : ff0;
            if (!val) f = 0.f;
            half8v hv = *(const half8v*)&xw1h[(size_t)src * 128 + 8 * q];
#pragma unroll
            for (int i = 0; i < 8; i++) acc[i] = fmaf((float)hv[i], f, acc[i]);
        }
    }
#pragma unroll
    for (int m = 32; m >= 16; m >>= 1) {
#pragma unroll
        for (int i = 0; i < 8; i++) acc[i] += __shfl_xor(acc[i], m);
    }
    if (lane < 16) {
        float sum = (q >= 8) ? sum1 : sum0;
        int c = 8 * q;
        float4 ba = *(const float4*)&b1[c];
        float4 bb = *(const float4*)&b1[c + 4];
        float4 o0, o1;
        o0.x = acc[0] / sum + ba.x; o0.y = acc[1] / sum + ba.y;
        o0.z = acc[2] / sum + ba.z; o0.w = acc[3] / sum + ba.w;
        o1.x = acc[4] / sum + bb.x; o1.y = acc[5] / sum + bb.y;
        o1.z = acc[6] / sum + bb.z; o1.w = acc[7] / sum + bb.w;
        o0.x = o0.x > 0.f ? o0.x : 0.f; o0.y = o0.y > 0.f ? o0.y : 0.f;
        o0.z = o0.z > 0.f ? o0.z : 0.f; o0.w = o0.w > 0.f ? o0.w : 0.f;
        o1.x = o1.x > 0.f ? o1.x : 0.f; o1.y = o1.y > 0.f ? o1.y : 0.f;
        o1.z = o1.z > 0.f ? o1.z : 0.f; o1.w = o1.w > 0.f ? o1.w : 0.f;
        *(float4*)&h[(size_t)n * 128 + c] = o0;
        *(float4*)&h[(size_t)n * 128 + c + 4] = o1;
    }
}

// ---------------- Layer 2 GEMM: 64 nodes/block, 4n x 4c tile ----------------

__global__ __launch_bounds__(256) void gemm2_kernel(
        const float* __restrict__ h, const float* __restrict__ W2,
        const float* __restrict__ att_src2, const float* __restrict__ att_dst2,
        _Float16* __restrict__ xw2h, float* __restrict__ as2, float* __restrict__ ad2) {
    __shared__ float xt[128 * 66];
    int tid = threadIdx.x;
    int base = blockIdx.x * 64;
#pragma unroll 4
    for (int it = 0; it < 32; ++it) {
        int e = it * 256 + tid;
        int nn = e >> 7, c = e & 127;
        float v = (base + nn < N_NODES) ? h[(size_t)base * 128 + e] : 0.f;
        xt[c * 66 + nn] = v;
    }
    __syncthreads();
    int cg = tid & 15, ng = tid >> 4;
    float acc[4][4];
#pragma unroll
    for (int i = 0; i < 4; i++)
#pragma unroll
        for (int j = 0; j < 4; j++) acc[i][j] = 0.f;

#pragma unroll 4
    for (int k = 0; k < 128; ++k) {
        float4 w = *(const float4*)&W2[k * 64 + 4 * cg];
        const float* xr = &xt[k * 66 + 4 * ng];
        float2 a0 = *(const float2*)&xr[0];
        float2 a1 = *(const float2*)&xr[2];
        float xv[4] = {a0.x, a0.y, a1.x, a1.y};
#pragma unroll
        for (int i = 0; i < 4; i++) {
            acc[i][0] = fmaf(xv[i], w.x, acc[i][0]);
            acc[i][1] = fmaf(xv[i], w.y, acc[i][1]);
            acc[i][2] = fmaf(xv[i], w.z, acc[i][2]);
            acc[i][3] = fmaf(xv[i], w.w, acc[i][3]);
        }
    }
    int c0 = 4 * cg;
    float s0 = att_src2[c0], s1 = att_src2[c0 + 1], s2 = att_src2[c0 + 2], s3 = att_src2[c0 + 3];
    float d0 = att_dst2[c0], d1 = att_dst2[c0 + 1], d2 = att_dst2[c0 + 2], d3 = att_dst2[c0 + 3];
#pragma unroll
    for (int i = 0; i < 4; i++) {
        int n = base + 4 * ng + i;
        bool ok = n < N_NODES;
        if (ok) {
            half4v hv;
            hv.x = (_Float16)acc[i][0]; hv.y = (_Float16)acc[i][1];
            hv.z = (_Float16)acc[i][2]; hv.w = (_Float16)acc[i][3];
            *(half4v*)&xw2h[(size_t)n * 64 + c0] = hv;
        }
        float ps = acc[i][0] * s0 + acc[i][1] * s1 + acc[i][2] * s2 + acc[i][3] * s3;
        float pd = acc[i][0] * d0 + acc[i][1] * d1 + acc[i][2] * d2 + acc[i][3] * d3;
#pragma unroll
        for (int m = 8; m >= 1; m >>= 1) {
            ps += __shfl_xor(ps, m);
            pd += __shfl_xor(pd, m);
        }
        if (ok && cg == 0) { as2[n] = ps; ad2[n] = pd; }
    }
}

// ---- Layer 2 aggregation: 8 edges/iter, half8 gathers, fused u/v epilogue ----

__global__ __launch_bounds__(256) void agg2_kernel(
        const int* __restrict__ off, const int* __restrict__ csr_src,
        const float* __restrict__ as2, const float* __restrict__ ad2,
        const _Float16* __restrict__ xw2h, const float* __restrict__ b2,
        const float* __restrict__ lw, float* __restrict__ u, float* __restrict__ v) {
    int wv = threadIdx.x >> 6, lane = threadIdx.x & 63;
    int n = blockIdx.x * 4 + wv;
    if (n >= N_NODES) return;
    int s = off[n], e = off[n + 1];
    float adn = ad2[n];
    int e8 = lane >> 3, q = lane & 7;       // edge slot 0..7; cols 8q..8q+7
    float acc[8];
#pragma unroll
    for (int i = 0; i < 8; i++) acc[i] = 0.f;
    float sum = 0.f;
    for (int b = s; b < e; b += 64) {
        int cnt = min(64, e - b);
        int l = lane < cnt ? lane : cnt - 1;
        int srcv = csr_src[b + l];
        float a = as2[srcv];
        float ev = a + adn; ev = ev > 0.f ? ev : NEG_SLOPE * ev;
        float fv = (lane < cnt) ? __expf(ev) : 0.f;
        float r = fv;
#pragma unroll
        for (int m = 32; m >= 1; m >>= 1) r += __shfl_xor(r, m);
        sum += r;
        for (int jj = 0; jj < cnt; jj += 8) {
            int j = jj + e8;
            bool val = j < cnt;
            int sl = val ? j : jj;
            int src = __shfl(srcv, sl);
            float f = __shfl(fv, sl);
            if (!val) f = 0.f;
            half8v hv = *(const half8v*)&xw2h[(size_t)src * 64 + 8 * q];
#pragma unroll
            for (int i = 0; i < 8; i++) acc[i] = fmaf((float)hv[i], f, acc[i]);
        }
    }
#pragma unroll
    for (int m = 32; m >= 8; m >>= 1) {
#pragma unroll
        for (int i = 0; i < 8; i++) acc[i] += __shfl_xor(acc[i], m);
    }
    // lanes 0..7 hold the final z row (cols 8q..8q+7); fuse link-pred dots
    int c = 8 * q;
    float pu = 0.f, pv = 0.f;
#pragma unroll
    for (int i = 0; i < 8; i++) {
        float zi = acc[i] / sum + b2[c + i];
        pu = fmaf(zi, lw[c + i], pu);
        pv = fmaf(zi, lw[64 + c + i], pv);
    }
#pragma unroll
    for (int m = 4; m >= 1; m >>= 1) {
        pu += __shfl_xor(pu, m);
        pv += __shfl_xor(pv, m);
    }
    if (lane == 0) { u[n] = pu; v[n] = pv; }
}

// ---------------- Link decode: out = u[s] + v[d] + lb ----------------

__global__ __launch_bounds__(256) void decode_kernel(
        const int* __restrict__ pos_ei, const int* __restrict__ neg_ei,
        const float* __restrict__ u, const float* __restrict__ v,
        const float* __restrict__ lb, float* __restrict__ out) {
    int idx = blockIdx.x * 256 + threadIdx.x;
    if (idx >= 2 * P_CAND) return;
    const int* ei; int p;
    if (idx < P_CAND) { ei = pos_ei; p = idx; }
    else              { ei = neg_ei; p = idx - P_CAND; }
    int sN = ei[p], dN = ei[P_CAND + p];
    out[idx] = u[sN] + v[dN] + lb[0];
}

// ---------------- launch ----------------

extern "C" void kernel_launch(void* const* d_in, const int* in_sizes, int n_in,
                              void* d_out, int out_size, void* d_ws, size_t ws_size,
                              hipStream_t stream) {
    const float* x        = (const float*)d_in[0];
    const int*   ei       = (const int*)d_in[1];
    const int*   pos_ei   = (const int*)d_in[3];
    const int*   neg_ei   = (const int*)d_in[4];
    const float* W1       = (const float*)d_in[5];
    const float* att_src1 = (const float*)d_in[6];
    const float* att_dst1 = (const float*)d_in[7];
    const float* b1       = (const float*)d_in[8];
    const float* W2       = (const float*)d_in[9];
    const float* att_src2 = (const float*)d_in[10];
    const float* att_dst2 = (const float*)d_in[11];
    const float* b2       = (const float*)d_in[12];
    const float* lw       = (const float*)d_in[13];
    const float* lb       = (const float*)d_in[14];
    float* out = (float*)d_out;

    char* ws = (char*)d_ws;
    size_t o = 0;
    auto alloc = [&](size_t bytes) -> char* {
        char* p = ws + o;
        o += (bytes + 511) & ~(size_t)511;
        return p;
    };
    _Float16* xw1h  = (_Float16*)alloc((size_t)N_NODES * 128 * 2);  // reused: xw2h
    float*    h     = (float*)alloc((size_t)N_NODES * 128 * 4);
    float*    u     = (float*)alloc((size_t)N_NODES * 4);
    float*    v     = (float*)alloc((size_t)N_NODES * 4);
    float*    as1   = (float*)alloc((size_t)N_NODES * 2 * 4);
    float*    ad1   = (float*)alloc((size_t)N_NODES * 2 * 4);
    float*    as2   = (float*)alloc((size_t)N_NODES * 4);
    float*    ad2   = (float*)alloc((size_t)N_NODES * 4);
    int*      off   = (int*)alloc((size_t)(N_NODES + 1) * 4);
    int*      hist  = (int*)alloc((size_t)NTOT * 4);
    int*      histS = (int*)alloc((size_t)NTOT * 4);
    unsigned* binned= (unsigned*)alloc((size_t)EP * 4);
    int*      csr   = (int*)alloc((size_t)EP * 4);
    _Float16* xw2h  = xw1h;    // xw1h dead after agg1

    hist_kernel<<<NB2, 256, 0, stream>>>(ei, hist);
    scan2_kernel<<<1, 1024, 0, stream>>>(hist, histS);
    scatterbin_kernel<<<NB2, 256, 0, stream>>>(ei, histS, binned);
    binsort_kernel<<<NBIN, 1024, 0, stream>>>(binned, histS, off, csr);
    gemm1_kernel<<<(N_NODES + 63) / 64, 256, 0, stream>>>(x, W1, att_src1, att_dst1, xw1h, as1, ad1);
    agg1_kernel<<<(N_NODES + 3) / 4, 256, 0, stream>>>(off, csr, as1, ad1, xw1h, b1, h);
    gemm2_kernel<<<(N_NODES + 63) / 64, 256, 0, stream>>>(h, W2, att_src2, att_dst2, xw2h, as2, ad2);
    agg2_kernel<<<(N_NODES + 3) / 4, 256, 0, stream>>>(off, csr, as2, ad2, xw2h, b2, lw, u, v);
    decode_kernel<<<(2 * P_CAND + 255) / 256, 256, 0, stream>>>(pos_ei, neg_ei, u, v, lb, out);
}

// Round 9
// 437.925 us; speedup vs baseline: 2.9618x; 1.0035x over previous
//
#include <hip/hip_runtime.h>

#define N_NODES 100000
#define E_EDGES 1600000
#define EP      (E_EDGES + N_NODES)   // edges + self loops = 1,700,000
#define P_CAND  262144
#define IN_C    128
#define HID     64
#define NEG_SLOPE 0.2f

#define NBIN  196            // ceil(100000/512) bins of 512 nodes
#define NB2   256            // blocks for hist/scatterbin
#define EPB   ((EP + NB2 - 1) / NB2)   // 6641 edges per block
#define NTOT  (NBIN * NB2)   // 50176 (= 1024*49)

#define XROW 72              // LDS row stride in halves (144 B, 16 B-aligned)

typedef _Float16 half4v __attribute__((ext_vector_type(4)));
typedef _Float16 half8v __attribute__((ext_vector_type(8)));

// ---------------- CSR build: deterministic 2-level counting sort ----------------

__global__ __launch_bounds__(256) void hist_kernel(const int* __restrict__ ei,
                                                   int* __restrict__ hist) {
    __shared__ int lh[NBIN];
    for (int t = threadIdx.x; t < NBIN; t += 256) lh[t] = 0;
    __syncthreads();
    int start = blockIdx.x * EPB;
    int end = min(start + EPB, EP);
    for (int i = start + threadIdx.x; i < end; i += 256) {
        int dst = (i < E_EDGES) ? ei[E_EDGES + i] : (i - E_EDGES);
        atomicAdd(&lh[dst >> 9], 1);
    }
    __syncthreads();
    for (int t = threadIdx.x; t < NBIN; t += 256) hist[t * NB2 + blockIdx.x] = lh[t];
}

__global__ __launch_bounds__(1024) void scan2_kernel(const int* __restrict__ hist,
                                                     int* __restrict__ histS) {
    __shared__ int s[1024];
    int t = threadIdx.x;
    int b0 = t * 49;                       // 1024*49 == 50176
    int sum = 0;
    for (int i = 0; i < 49; i++) sum += hist[b0 + i];
    s[t] = sum;
    __syncthreads();
    for (int d = 1; d < 1024; d <<= 1) {
        int v = (t >= d) ? s[t - d] : 0;
        __syncthreads();
        s[t] += v;
        __syncthreads();
    }
    int run = s[t] - sum;
    for (int i = 0; i < 49; i++) { int hv = hist[b0 + i]; histS[b0 + i] = run; run += hv; }
}

__global__ __launch_bounds__(256) void scatterbin_kernel(const int* __restrict__ ei,
                                                         const int* __restrict__ histS,
                                                         unsigned* __restrict__ binned) {
    __shared__ int cur[NBIN];
    for (int t = threadIdx.x; t < NBIN; t += 256) cur[t] = histS[t * NB2 + blockIdx.x];
    __syncthreads();
    int start = blockIdx.x * EPB;
    int end = min(start + EPB, EP);
    for (int i = start + threadIdx.x; i < end; i += 256) {
        int src, dst;
        if (i < E_EDGES) { src = ei[i]; dst = ei[E_EDGES + i]; }
        else             { src = i - E_EDGES; dst = src; }
        int pos = atomicAdd(&cur[dst >> 9], 1);
        binned[pos] = (unsigned)src | ((unsigned)(dst & 511) << 17);
    }
}

__global__ __launch_bounds__(1024) void binsort_kernel(const unsigned* __restrict__ binned,
                                                       const int* __restrict__ histS,
                                                       int* __restrict__ off,
                                                       int* __restrict__ csr) {
    __shared__ int lh[512];
    __shared__ int lsc[512];
    int b = blockIdx.x, t = threadIdx.x;
    int base = histS[b * NB2];
    int endv = (b == NBIN - 1) ? EP : histS[(b + 1) * NB2];
    if (t < 512) lh[t] = 0;
    __syncthreads();
    for (int i = base + t; i < endv; i += 1024)
        atomicAdd(&lh[binned[i] >> 17], 1);
    __syncthreads();
    if (t < 512) lsc[t] = lh[t];
    __syncthreads();
    for (int d = 1; d < 512; d <<= 1) {
        int v = (t >= d && t < 512) ? lsc[t - d] : 0;
        __syncthreads();
        if (t < 512) lsc[t] += v;
        __syncthreads();
    }
    if (t < 512) {
        int ex = lsc[t] - lh[t];
        int node = b * 512 + t;
        if (node <= N_NODES) off[node] = base + ex;
        lh[t] = base + ex;
    }
    __syncthreads();
    for (int i = base + t; i < endv; i += 1024) {
        unsigned v = binned[i];
        int pos = atomicAdd(&lh[v >> 17], 1);
        csr[pos] = (int)(v & 0x1FFFFu);
    }
}

// ---------------- Layer 1 GEMM: 64 nodes/block, fp16 LDS staging, 8n x 4c tile ------

__global__ __launch_bounds__(256) void gemm1_kernel(
        const float* __restrict__ x, const float* __restrict__ W1,
        const float* __restrict__ att_src1, const float* __restrict__ att_dst1,
        _Float16* __restrict__ xw1h, float* __restrict__ as1, float* __restrict__ ad1) {
    __shared__ _Float16 xt[128 * XROW];      // xt[k][node], fp16, 18.4 KB
    int tid = threadIdx.x;
    int base = blockIdx.x * 64;
#pragma unroll 4
    for (int it = 0; it < 32; ++it) {
        int e = it * 256 + tid;
        int nn = e >> 7, c = e & 127;
        float v = (base + nn < N_NODES) ? x[(size_t)base * 128 + e] : 0.f;
        xt[c * XROW + nn] = (_Float16)v;
    }
    __syncthreads();
    int cg = tid & 31, ng = tid >> 5;
    float acc[8][4];
#pragma unroll
    for (int i = 0; i < 8; i++)
#pragma unroll
        for (int j = 0; j < 4; j++) acc[i][j] = 0.f;

#pragma unroll 4
    for (int k = 0; k < 128; ++k) {
        float4 w = *(const float4*)&W1[k * 128 + 4 * cg];
        half8v hx = *(const half8v*)&xt[k * XROW + 8 * ng];   // one ds_read_b128
#pragma unroll
        for (int i = 0; i < 8; i++) {
            float xv = (float)hx[i];
            acc[i][0] = fmaf(xv, w.x, acc[i][0]);
            acc[i][1] = fmaf(xv, w.y, acc[i][1]);
            acc[i][2] = fmaf(xv, w.z, acc[i][2]);
            acc[i][3] = fmaf(xv, w.w, acc[i][3]);
        }
    }
    int c0 = 4 * cg;
    float s0 = att_src1[c0], s1 = att_src1[c0 + 1], s2 = att_src1[c0 + 2], s3 = att_src1[c0 + 3];
    float d0 = att_dst1[c0], d1 = att_dst1[c0 + 1], d2 = att_dst1[c0 + 2], d3 = att_dst1[c0 + 3];
#pragma unroll
    for (int i = 0; i < 8; i++) {
        int n = base + 8 * ng + i;
        bool ok = n < N_NODES;
        if (ok) {
            half4v hv;
            hv.x = (_Float16)acc[i][0]; hv.y = (_Float16)acc[i][1];
            hv.z = (_Float16)acc[i][2]; hv.w = (_Float16)acc[i][3];
            *(half4v*)&xw1h[(size_t)n * 128 + c0] = hv;
        }
        float ps = acc[i][0] * s0 + acc[i][1] * s1 + acc[i][2] * s2 + acc[i][3] * s3;
        float pd = acc[i][0] * d0 + acc[i][1] * d1 + acc[i][2] * d2 + acc[i][3] * d3;
#pragma unroll
        for (int m = 8; m >= 1; m >>= 1) {
            ps += __shfl_xor(ps, m);
            pd += __shfl_xor(pd, m);
        }
        if (ok && (cg == 0 || cg == 16)) {
            int hh = cg >> 4;
            as1[n * 2 + hh] = ps;
            ad1[n * 2 + hh] = pd;
        }
    }
}

// ---- Layer 1 aggregation: one wave per node, 4 edges/iter, half8 (16B) gathers ----

__global__ __launch_bounds__(256) void agg1_kernel(
        const int* __restrict__ off, const int* __restrict__ csr_src,
        const float* __restrict__ as1, const float* __restrict__ ad1,
        const _Float16* __restrict__ xw1h, const float* __restrict__ b1,
        float* __restrict__ h) {
    int wv = threadIdx.x >> 6, lane = threadIdx.x & 63;
    int n = blockIdx.x * 4 + wv;
    if (n >= N_NODES) return;
    int s = off[n], e = off[n + 1];
    float adn0 = ad1[2 * n], adn1 = ad1[2 * n + 1];
    int e4 = lane >> 4, q = lane & 15;      // edge slot 0..3; cols 8q..8q+7 (q<8:head0)
    float acc[8];
#pragma unroll
    for (int i = 0; i < 8; i++) acc[i] = 0.f;
    float sum0 = 0.f, sum1 = 0.f;
    for (int b = s; b < e; b += 64) {
        int cnt = min(64, e - b);
        int l = lane < cnt ? lane : cnt - 1;
        int srcv = csr_src[b + l];
        float2 a = *(const float2*)&as1[2 * srcv];
        float e0 = a.x + adn0; e0 = e0 > 0.f ? e0 : NEG_SLOPE * e0;
        float e1 = a.y + adn1; e1 = e1 > 0.f ? e1 : NEG_SLOPE * e1;
        float f0v = (lane < cnt) ? __expf(e0) : 0.f;
        float f1v = (lane < cnt) ? __expf(e1) : 0.f;
        float r0 = f0v, r1 = f1v;
#pragma unroll
        for (int m = 32; m >= 1; m >>= 1) { r0 += __shfl_xor(r0, m); r1 += __shfl_xor(r1, m); }
        sum0 += r0; sum1 += r1;
        for (int jj = 0; jj < cnt; jj += 4) {
            int j = jj + e4;
            bool val = j < cnt;
            int sl = val ? j : jj;
            int src = __shfl(srcv, sl);
            float ff0 = __shfl(f0v, sl);
            float ff1 = __shfl(f1v, sl);
            float f = (q >= 8) ? ff1 : ff0;
            if (!val) f = 0.f;
            half8v hv = *(const half8v*)&xw1h[(size_t)src * 128 + 8 * q];
#pragma unroll
            for (int i = 0; i < 8; i++) acc[i] = fmaf((float)hv[i], f, acc[i]);
        }
    }
#pragma unroll
    for (int m = 32; m >= 16; m >>= 1) {
#pragma unroll
        for (int i = 0; i < 8; i++) acc[i] += __shfl_xor(acc[i], m);
    }
    if (lane < 16) {
        float sum = (q >= 8) ? sum1 : sum0;
        int c = 8 * q;
        float4 ba = *(const float4*)&b1[c];
        float4 bb = *(const float4*)&b1[c + 4];
        float4 o0, o1;
        o0.x = acc[0] / sum + ba.x; o0.y = acc[1] / sum + ba.y;
        o0.z = acc[2] / sum + ba.z; o0.w = acc[3] / sum + ba.w;
        o1.x = acc[4] / sum + bb.x; o1.y = acc[5] / sum + bb.y;
        o1.z = acc[6] / sum + bb.z; o1.w = acc[7] / sum + bb.w;
        o0.x = o0.x > 0.f ? o0.x : 0.f; o0.y = o0.y > 0.f ? o0.y : 0.f;
        o0.z = o0.z > 0.f ? o0.z : 0.f; o0.w = o0.w > 0.f ? o0.w : 0.f;
        o1.x = o1.x > 0.f ? o1.x : 0.f; o1.y = o1.y > 0.f ? o1.y : 0.f;
        o1.z = o1.z > 0.f ? o1.z : 0.f; o1.w = o1.w > 0.f ? o1.w : 0.f;
        *(float4*)&h[(size_t)n * 128 + c] = o0;
        *(float4*)&h[(size_t)n * 128 + c + 4] = o1;
    }
}

// ---------------- Layer 2 GEMM: 64 nodes/block, fp16 LDS staging, 4n x 4c tile ------

__global__ __launch_bounds__(256) void gemm2_kernel(
        const float* __restrict__ h, const float* __restrict__ W2,
        const float* __restrict__ att_src2, const float* __restrict__ att_dst2,
        _Float16* __restrict__ xw2h, float* __restrict__ as2, float* __restrict__ ad2) {
    __shared__ _Float16 xt[128 * XROW];
    int tid = threadIdx.x;
    int base = blockIdx.x * 64;
#pragma unroll 4
    for (int it = 0; it < 32; ++it) {
        int e = it * 256 + tid;
        int nn = e >> 7, c = e & 127;
        float v = (base + nn < N_NODES) ? h[(size_t)base * 128 + e] : 0.f;
        xt[c * XROW + nn] = (_Float16)v;
    }
    __syncthreads();
    int cg = tid & 15, ng = tid >> 4;
    float acc[4][4];
#pragma unroll
    for (int i = 0; i < 4; i++)
#pragma unroll
        for (int j = 0; j < 4; j++) acc[i][j] = 0.f;

#pragma unroll 4
    for (int k = 0; k < 128; ++k) {
        float4 w = *(const float4*)&W2[k * 64 + 4 * cg];
        half4v hx = *(const half4v*)&xt[k * XROW + 4 * ng];   // one ds_read_b64
#pragma unroll
        for (int i = 0; i < 4; i++) {
            float xv = (float)hx[i];
            acc[i][0] = fmaf(xv, w.x, acc[i][0]);
            acc[i][1] = fmaf(xv, w.y, acc[i][1]);
            acc[i][2] = fmaf(xv, w.z, acc[i][2]);
            acc[i][3] = fmaf(xv, w.w, acc[i][3]);
        }
    }
    int c0 = 4 * cg;
    float s0 = att_src2[c0], s1 = att_src2[c0 + 1], s2 = att_src2[c0 + 2], s3 = att_src2[c0 + 3];
    float d0 = att_dst2[c0], d1 = att_dst2[c0 + 1], d2 = att_dst2[c0 + 2], d3 = att_dst2[c0 + 3];
#pragma unroll
    for (int i = 0; i < 4; i++) {
        int n = base + 4 * ng + i;
        bool ok = n < N_NODES;
        if (ok) {
            half4v hv;
            hv.x = (_Float16)acc[i][0]; hv.y = (_Float16)acc[i][1];
            hv.z = (_Float16)acc[i][2]; hv.w = (_Float16)acc[i][3];
            *(half4v*)&xw2h[(size_t)n * 64 + c0] = hv;
        }
        float ps = acc[i][0] * s0 + acc[i][1] * s1 + acc[i][2] * s2 + acc[i][3] * s3;
        float pd = acc[i][0] * d0 + acc[i][1] * d1 + acc[i][2] * d2 + acc[i][3] * d3;
#pragma unroll
        for (int m = 8; m >= 1; m >>= 1) {
            ps += __shfl_xor(ps, m);
            pd += __shfl_xor(pd, m);
        }
        if (ok && cg == 0) { as2[n] = ps; ad2[n] = pd; }
    }
}

// ---- Layer 2 aggregation: 8 edges/iter, half8 gathers, fused u/v epilogue ----

__global__ __launch_bounds__(256) void agg2_kernel(
        const int* __restrict__ off, const int* __restrict__ csr_src,
        const float* __restrict__ as2, const float* __restrict__ ad2,
        const _Float16* __restrict__ xw2h, const float* __restrict__ b2,
        const float* __restrict__ lw, float* __restrict__ u, float* __restrict__ v) {
    int wv = threadIdx.x >> 6, lane = threadIdx.x & 63;
    int n = blockIdx.x * 4 + wv;
    if (n >= N_NODES) return;
    int s = off[n], e = off[n + 1];
    float adn = ad2[n];
    int e8 = lane >> 3, q = lane & 7;       // edge slot 0..7; cols 8q..8q+7
    float acc[8];
#pragma unroll
    for (int i = 0; i < 8; i++) acc[i] = 0.f;
    float sum = 0.f;
    for (int b = s; b < e; b += 64) {
        int cnt = min(64, e - b);
        int l = lane < cnt ? lane : cnt - 1;
        int srcv = csr_src[b + l];
        float a = as2[srcv];
        float ev = a + adn; ev = ev > 0.f ? ev : NEG_SLOPE * ev;
        float fv = (lane < cnt) ? __expf(ev) : 0.f;
        float r = fv;
#pragma unroll
        for (int m = 32; m >= 1; m >>= 1) r += __shfl_xor(r, m);
        sum += r;
        for (int jj = 0; jj < cnt; jj += 8) {
            int j = jj + e8;
            bool val = j < cnt;
            int sl = val ? j : jj;
            int src = __shfl(srcv, sl);
            float f = __shfl(fv, sl);
            if (!val) f = 0.f;
            half8v hv = *(const half8v*)&xw2h[(size_t)src * 64 + 8 * q];
#pragma unroll
            for (int i = 0; i < 8; i++) acc[i] = fmaf((float)hv[i], f, acc[i]);
        }
    }
#pragma unroll
    for (int m = 32; m >= 8; m >>= 1) {
#pragma unroll
        for (int i = 0; i < 8; i++) acc[i] += __shfl_xor(acc[i], m);
    }
    // lanes 0..7 hold the final z row (cols 8q..8q+7); fuse link-pred dots
    int c = 8 * q;
    float pu = 0.f, pv = 0.f;
#pragma unroll
    for (int i = 0; i < 8; i++) {
        float zi = acc[i] / sum + b2[c + i];
        pu = fmaf(zi, lw[c + i], pu);
        pv = fmaf(zi, lw[64 + c + i], pv);
    }
#pragma unroll
    for (int m = 4; m >= 1; m >>= 1) {
        pu += __shfl_xor(pu, m);
        pv += __shfl_xor(pv, m);
    }
    if (lane == 0) { u[n] = pu; v[n] = pv; }
}

// ---------------- Link decode: out = u[s] + v[d] + lb ----------------

__global__ __launch_bounds__(256) void decode_kernel(
        const int* __restrict__ pos_ei, const int* __restrict__ neg_ei,
        const float* __restrict__ u, const float* __restrict__ v,
        const float* __restrict__ lb, float* __restrict__ out) {
    int idx = blockIdx.x * 256 + threadIdx.x;
    if (idx >= 2 * P_CAND) return;
    const int* ei; int p;
    if (idx < P_CAND) { ei = pos_ei; p = idx; }
    else              { ei = neg_ei; p = idx - P_CAND; }
    int sN = ei[p], dN = ei[P_CAND + p];
    out[idx] = u[sN] + v[dN] + lb[0];
}

// ---------------- launch ----------------

extern "C" void kernel_launch(void* const* d_in, const int* in_sizes, int n_in,
                              void* d_out, int out_size, void* d_ws, size_t ws_size,
                              hipStream_t stream) {
    const float* x        = (const float*)d_in[0];
    const int*   ei       = (const int*)d_in[1];
    const int*   pos_ei   = (const int*)d_in[3];
    const int*   neg_ei   = (const int*)d_in[4];
    const float* W1       = (const float*)d_in[5];
    const float* att_src1 = (const float*)d_in[6];
    const float* att_dst1 = (const float*)d_in[7];
    const float* b1       = (const float*)d_in[8];
    const float* W2       = (const float*)d_in[9];
    const float* att_src2 = (const float*)d_in[10];
    const float* att_dst2 = (const float*)d_in[11];
    const float* b2       = (const float*)d_in[12];
    const float* lw       = (const float*)d_in[13];
    const float* lb       = (const float*)d_in[14];
    float* out = (float*)d_out;

    char* ws = (char*)d_ws;
    size_t o = 0;
    auto alloc = [&](size_t bytes) -> char* {
        char* p = ws + o;
        o += (bytes + 511) & ~(size_t)511;
        return p;
    };
    _Float16* xw1h  = (_Float16*)alloc((size_t)N_NODES * 128 * 2);  // reused: xw2h
    float*    h     = (float*)alloc((size_t)N_NODES * 128 * 4);
    float*    u     = (float*)alloc((size_t)N_NODES * 4);
    float*    v     = (float*)alloc((size_t)N_NODES * 4);
    float*    as1   = (float*)alloc((size_t)N_NODES * 2 * 4);
    float*    ad1   = (float*)alloc((size_t)N_NODES * 2 * 4);
    float*    as2   = (float*)alloc((size_t)N_NODES * 4);
    float*    ad2   = (float*)alloc((size_t)N_NODES * 4);
    int*      off   = (int*)alloc((size_t)(N_NODES + 1) * 4);
    int*      hist  = (int*)alloc((size_t)NTOT * 4);
    int*      histS = (int*)alloc((size_t)NTOT * 4);
    unsigned* binned= (unsigned*)alloc((size_t)EP * 4);
    int*      csr   = (int*)alloc((size_t)EP * 4);
    _Float16* xw2h  = xw1h;    // xw1h dead after agg1

    hist_kernel<<<NB2, 256, 0, stream>>>(ei, hist);
    scan2_kernel<<<1, 1024, 0, stream>>>(hist, histS);
    scatterbin_kernel<<<NB2, 256, 0, stream>>>(ei, histS, binned);
    binsort_kernel<<<NBIN, 1024, 0, stream>>>(binned, histS, off, csr);
    gemm1_kernel<<<(N_NODES + 63) / 64, 256, 0, stream>>>(x, W1, att_src1, att_dst1, xw1h, as1, ad1);
    agg1_kernel<<<(N_NODES + 3) / 4, 256, 0, stream>>>(off, csr, as1, ad1, xw1h, b1, h);
    gemm2_kernel<<<(N_NODES + 63) / 64, 256, 0, stream>>>(h, W2, att_src2, att_dst2, xw2h, as2, ad2);
    agg2_kernel<<<(N_NODES + 3) / 4, 256, 0, stream>>>(off, csr, as2, ad2, xw2h, b2, lw, u, v);
    decode_kernel<<<(2 * P_CAND + 255) / 256, 256, 0, stream>>>(pos_ei, neg_ei, u, v, lb, out);
}

// Round 10
// 416.775 us; speedup vs baseline: 3.1121x; 1.0507x over previous
//
#include <hip/hip_runtime.h>

#define N_NODES 100000
#define E_EDGES 1600000
#define EP      (E_EDGES + N_NODES)   // edges + self loops = 1,700,000
#define P_CAND  262144
#define IN_C    128
#define HID     64
#define NEG_SLOPE 0.2f

#define NBIN  196            // ceil(100000/512) bins of 512 nodes
#define NB2   256            // blocks for hist/scatterbin
#define EPB   ((EP + NB2 - 1) / NB2)   // 6641 edges per block
#define NTOT  (NBIN * NB2)   // 50176 (= 1024*49)

typedef _Float16 half4v __attribute__((ext_vector_type(4)));
typedef _Float16 half8v __attribute__((ext_vector_type(8)));
typedef float    float4v __attribute__((ext_vector_type(4)));

// ---------------- CSR build: deterministic 2-level counting sort ----------------

__global__ __launch_bounds__(256) void hist_kernel(const int* __restrict__ ei,
                                                   int* __restrict__ hist) {
    __shared__ int lh[NBIN];
    for (int t = threadIdx.x; t < NBIN; t += 256) lh[t] = 0;
    __syncthreads();
    int start = blockIdx.x * EPB;
    int end = min(start + EPB, EP);
    for (int i = start + threadIdx.x; i < end; i += 256) {
        int dst = (i < E_EDGES) ? ei[E_EDGES + i] : (i - E_EDGES);
        atomicAdd(&lh[dst >> 9], 1);
    }
    __syncthreads();
    for (int t = threadIdx.x; t < NBIN; t += 256) hist[t * NB2 + blockIdx.x] = lh[t];
}

__global__ __launch_bounds__(1024) void scan2_kernel(const int* __restrict__ hist,
                                                     int* __restrict__ histS) {
    __shared__ int s[1024];
    int t = threadIdx.x;
    int b0 = t * 49;                       // 1024*49 == 50176
    int sum = 0;
    for (int i = 0; i < 49; i++) sum += hist[b0 + i];
    s[t] = sum;
    __syncthreads();
    for (int d = 1; d < 1024; d <<= 1) {
        int v = (t >= d) ? s[t - d] : 0;
        __syncthreads();
        s[t] += v;
        __syncthreads();
    }
    int run = s[t] - sum;
    for (int i = 0; i < 49; i++) { int hv = hist[b0 + i]; histS[b0 + i] = run; run += hv; }
}

__global__ __launch_bounds__(256) void scatterbin_kernel(const int* __restrict__ ei,
                                                         const int* __restrict__ histS,
                                                         unsigned* __restrict__ binned) {
    __shared__ int cur[NBIN];
    for (int t = threadIdx.x; t < NBIN; t += 256) cur[t] = histS[t * NB2 + blockIdx.x];
    __syncthreads();
    int start = blockIdx.x * EPB;
    int end = min(start + EPB, EP);
    for (int i = start + threadIdx.x; i < end; i += 256) {
        int src, dst;
        if (i < E_EDGES) { src = ei[i]; dst = ei[E_EDGES + i]; }
        else             { src = i - E_EDGES; dst = src; }
        int pos = atomicAdd(&cur[dst >> 9], 1);
        binned[pos] = (unsigned)src | ((unsigned)(dst & 511) << 17);
    }
}

__global__ __launch_bounds__(1024) void binsort_kernel(const unsigned* __restrict__ binned,
                                                       const int* __restrict__ histS,
                                                       int* __restrict__ off,
                                                       int* __restrict__ csr) {
    __shared__ int lh[512];
    __shared__ int lsc[512];
    int b = blockIdx.x, t = threadIdx.x;
    int base = histS[b * NB2];
    int endv = (b == NBIN - 1) ? EP : histS[(b + 1) * NB2];
    if (t < 512) lh[t] = 0;
    __syncthreads();
    for (int i = base + t; i < endv; i += 1024)
        atomicAdd(&lh[binned[i] >> 17], 1);
    __syncthreads();
    if (t < 512) lsc[t] = lh[t];
    __syncthreads();
    for (int d = 1; d < 512; d <<= 1) {
        int v = (t >= d && t < 512) ? lsc[t - d] : 0;
        __syncthreads();
        if (t < 512) lsc[t] += v;
        __syncthreads();
    }
    if (t < 512) {
        int ex = lsc[t] - lh[t];
        int node = b * 512 + t;
        if (node <= N_NODES) off[node] = base + ex;
        lh[t] = base + ex;
    }
    __syncthreads();
    for (int i = base + t; i < endv; i += 1024) {
        unsigned v = binned[i];
        int pos = atomicAdd(&lh[v >> 17], 1);
        csr[pos] = (int)(v & 0x1FFFFu);
    }
}

// ---------------- Weight prep: fp16 transposed copies (L2-resident) ----------------

__global__ __launch_bounds__(256) void prep_kernel(const float* __restrict__ W1,
                                                   const float* __restrict__ W2,
                                                   _Float16* __restrict__ W1T,
                                                   _Float16* __restrict__ W2T) {
    int idx = blockIdx.x * 256 + threadIdx.x;
    if (idx < 128 * 128) {
        int col = idx >> 7, k = idx & 127;
        W1T[idx] = (_Float16)W1[k * 128 + col];
    } else if (idx < 128 * 128 + 64 * 128) {
        int i2 = idx - 128 * 128;
        int col = i2 >> 7, k = i2 & 127;
        W2T[i2] = (_Float16)W2[k * 64 + col];
    }
}

// ---------------- Layer 1 GEMM: MFMA 16x16x32_f16, 64 nodes/block ----------------
// wave w: nodes base+16w..+15 (M-tile); 8 N-tiles of 16 cols; K=128 in 4 steps.
// A[m=lq][k=quad*8+j] from LDS xs[node][k]; B[k=quad*8+j][n=lq] from W1T[col][k].
// C/D: col=lq, row=quad*4+r.

__global__ __launch_bounds__(256) void gemm1_kernel(
        const float* __restrict__ x, const _Float16* __restrict__ W1T,
        const float* __restrict__ att_src1, const float* __restrict__ att_dst1,
        _Float16* __restrict__ xw1h, float* __restrict__ as1, float* __restrict__ ad1) {
    __shared__ _Float16 xs[64 * 136];       // [node][k], stride 272 B (16B mult)
    int tid = threadIdx.x;
    int base = blockIdx.x * 64;
#pragma unroll 4
    for (int it = 0; it < 32; ++it) {
        int e = it * 256 + tid;
        int nn = e >> 7, k = e & 127;
        float v = (base + nn < N_NODES) ? x[(size_t)base * 128 + e] : 0.f;
        xs[nn * 136 + k] = (_Float16)v;
    }
    __syncthreads();
    int w = tid >> 6, l = tid & 63;
    int quad = l >> 4, lq = l & 15;
    float4v acc[8];
#pragma unroll
    for (int t = 0; t < 8; t++) acc[t] = (float4v)0.f;
    const _Float16* arow = &xs[(16 * w + lq) * 136];
#pragma unroll
    for (int ks = 0; ks < 4; ++ks) {
        half8v a = *(const half8v*)&arow[ks * 32 + quad * 8];
#pragma unroll
        for (int t = 0; t < 8; t++) {
            half8v b = *(const half8v*)&W1T[(t * 16 + lq) * 128 + ks * 32 + quad * 8];
            acc[t] = __builtin_amdgcn_mfma_f32_16x16x32_f16(a, b, acc[t], 0, 0, 0);
        }
    }
    // attention dots from fp32 accumulators
    float s_att[8], d_att[8];
#pragma unroll
    for (int t = 0; t < 8; t++) {
        s_att[t] = att_src1[t * 16 + lq];
        d_att[t] = att_dst1[t * 16 + lq];
    }
#pragma unroll
    for (int r = 0; r < 4; r++) {
        float ps0 = 0.f, ps1 = 0.f, pd0 = 0.f, pd1 = 0.f;
#pragma unroll
        for (int t = 0; t < 4; t++) {
            ps0 = fmaf(acc[t][r], s_att[t], ps0);
            pd0 = fmaf(acc[t][r], d_att[t], pd0);
            ps1 = fmaf(acc[t + 4][r], s_att[t + 4], ps1);
            pd1 = fmaf(acc[t + 4][r], d_att[t + 4], pd1);
        }
#pragma unroll
        for (int m = 8; m >= 1; m >>= 1) {
            ps0 += __shfl_xor(ps0, m); ps1 += __shfl_xor(ps1, m);
            pd0 += __shfl_xor(pd0, m); pd1 += __shfl_xor(pd1, m);
        }
        int n = base + 16 * w + quad * 4 + r;
        if (lq == 0 && n < N_NODES) {
            as1[n * 2] = ps0; as1[n * 2 + 1] = ps1;
            ad1[n * 2] = pd0; ad1[n * 2 + 1] = pd1;
        }
    }
    // xw1h store via LDS roundtrip -> coalesced half8 stores
    __syncthreads();
#pragma unroll
    for (int t = 0; t < 8; t++)
#pragma unroll
        for (int r = 0; r < 4; r++)
            xs[(16 * w + quad * 4 + r) * 136 + t * 16 + lq] = (_Float16)acc[t][r];
    __syncthreads();
    int node = tid >> 2, seg = tid & 3;
    if (base + node < N_NODES) {
#pragma unroll
        for (int i = 0; i < 4; i++) {
            half8v vv = *(const half8v*)&xs[node * 136 + seg * 32 + i * 8];
            *(half8v*)&xw1h[(size_t)(base + node) * 128 + seg * 32 + i * 8] = vv;
        }
    }
}

// ---- Layer 1 aggregation: one wave per node, 4 edges/iter, half8 (16B) gathers ----

__global__ __launch_bounds__(256) void agg1_kernel(
        const int* __restrict__ off, const int* __restrict__ csr_src,
        const float* __restrict__ as1, const float* __restrict__ ad1,
        const _Float16* __restrict__ xw1h, const float* __restrict__ b1,
        float* __restrict__ h) {
    int wv = threadIdx.x >> 6, lane = threadIdx.x & 63;
    int n = blockIdx.x * 4 + wv;
    if (n >= N_NODES) return;
    int s = off[n], e = off[n + 1];
    float adn0 = ad1[2 * n], adn1 = ad1[2 * n + 1];
    int e4 = lane >> 4, q = lane & 15;      // edge slot 0..3; cols 8q..8q+7 (q<8:head0)
    float acc[8];
#pragma unroll
    for (int i = 0; i < 8; i++) acc[i] = 0.f;
    float sum0 = 0.f, sum1 = 0.f;
    for (int b = s; b < e; b += 64) {
        int cnt = min(64, e - b);
        int l = lane < cnt ? lane : cnt - 1;
        int srcv = csr_src[b + l];
        float2 a = *(const float2*)&as1[2 * srcv];
        float e0 = a.x + adn0; e0 = e0 > 0.f ? e0 : NEG_SLOPE * e0;
        float e1 = a.y + adn1; e1 = e1 > 0.f ? e1 : NEG_SLOPE * e1;
        float f0v = (lane < cnt) ? __expf(e0) : 0.f;
        float f1v = (lane < cnt) ? __expf(e1) : 0.f;
        float r0 = f0v, r1 = f1v;
#pragma unroll
        for (int m = 32; m >= 1; m >>= 1) { r0 += __shfl_xor(r0, m); r1 += __shfl_xor(r1, m); }
        sum0 += r0; sum1 += r1;
        for (int jj = 0; jj < cnt; jj += 4) {
            int j = jj + e4;
            bool val = j < cnt;
            int sl = val ? j : jj;
            int src = __shfl(srcv, sl);
            float ff0 = __shfl(f0v, sl);
            float ff1 = __shfl(f1v, sl);
            float f = (q >= 8) ? ff1 : ff0;
            if (!val) f = 0.f;
            half8v hv = *(const half8v*)&xw1h[(size_t)src * 128 + 8 * q];
#pragma unroll
            for (int i = 0; i < 8; i++) acc[i] = fmaf((float)hv[i], f, acc[i]);
        }
    }
#pragma unroll
    for (int m = 32; m >= 16; m >>= 1) {
#pragma unroll
        for (int i = 0; i < 8; i++) acc[i] += __shfl_xor(acc[i], m);
    }
    if (lane < 16) {
        float sum = (q >= 8) ? sum1 : sum0;
        int c = 8 * q;
        float4 ba = *(const float4*)&b1[c];
        float4 bb = *(const float4*)&b1[c + 4];
        float4 o0, o1;
        o0.x = acc[0] / sum + ba.x; o0.y = acc[1] / sum + ba.y;
        o0.z = acc[2] / sum + ba.z; o0.w = acc[3] / sum + ba.w;
        o1.x = acc[4] / sum + bb.x; o1.y = acc[5] / sum + bb.y;
        o1.z = acc[6] / sum + bb.z; o1.w = acc[7] / sum + bb.w;
        o0.x = o0.x > 0.f ? o0.x : 0.f; o0.y = o0.y > 0.f ? o0.y : 0.f;
        o0.z = o0.z > 0.f ? o0.z : 0.f; o0.w = o0.w > 0.f ? o0.w : 0.f;
        o1.x = o1.x > 0.f ? o1.x : 0.f; o1.y = o1.y > 0.f ? o1.y : 0.f;
        o1.z = o1.z > 0.f ? o1.z : 0.f; o1.w = o1.w > 0.f ? o1.w : 0.f;
        *(float4*)&h[(size_t)n * 128 + c] = o0;
        *(float4*)&h[(size_t)n * 128 + c + 4] = o1;
    }
}

// ---------------- Layer 2 GEMM: MFMA 16x16x32_f16, 64 nodes/block, N=64 ------------

__global__ __launch_bounds__(256) void gemm2_kernel(
        const float* __restrict__ h, const _Float16* __restrict__ W2T,
        const float* __restrict__ att_src2, const float* __restrict__ att_dst2,
        _Float16* __restrict__ xw2h, float* __restrict__ as2, float* __restrict__ ad2) {
    __shared__ _Float16 xs[64 * 136];
    int tid = threadIdx.x;
    int base = blockIdx.x * 64;
#pragma unroll 4
    for (int it = 0; it < 32; ++it) {
        int e = it * 256 + tid;
        int nn = e >> 7, k = e & 127;
        float v = (base + nn < N_NODES) ? h[(size_t)base * 128 + e] : 0.f;
        xs[nn * 136 + k] = (_Float16)v;
    }
    __syncthreads();
    int w = tid >> 6, l = tid & 63;
    int quad = l >> 4, lq = l & 15;
    float4v acc[4];
#pragma unroll
    for (int t = 0; t < 4; t++) acc[t] = (float4v)0.f;
    const _Float16* arow = &xs[(16 * w + lq) * 136];
#pragma unroll
    for (int ks = 0; ks < 4; ++ks) {
        half8v a = *(const half8v*)&arow[ks * 32 + quad * 8];
#pragma unroll
        for (int t = 0; t < 4; t++) {
            half8v b = *(const half8v*)&W2T[(t * 16 + lq) * 128 + ks * 32 + quad * 8];
            acc[t] = __builtin_amdgcn_mfma_f32_16x16x32_f16(a, b, acc[t], 0, 0, 0);
        }
    }
    float s_att[4], d_att[4];
#pragma unroll
    for (int t = 0; t < 4; t++) {
        s_att[t] = att_src2[t * 16 + lq];
        d_att[t] = att_dst2[t * 16 + lq];
    }
#pragma unroll
    for (int r = 0; r < 4; r++) {
        float ps = 0.f, pd = 0.f;
#pragma unroll
        for (int t = 0; t < 4; t++) {
            ps = fmaf(acc[t][r], s_att[t], ps);
            pd = fmaf(acc[t][r], d_att[t], pd);
        }
#pragma unroll
        for (int m = 8; m >= 1; m >>= 1) {
            ps += __shfl_xor(ps, m);
            pd += __shfl_xor(pd, m);
        }
        int n = base + 16 * w + quad * 4 + r;
        if (lq == 0 && n < N_NODES) { as2[n] = ps; ad2[n] = pd; }
    }
    __syncthreads();
#pragma unroll
    for (int t = 0; t < 4; t++)
#pragma unroll
        for (int r = 0; r < 4; r++)
            xs[(16 * w + quad * 4 + r) * 72 + t * 16 + lq] = (_Float16)acc[t][r];
    __syncthreads();
#pragma unroll
    for (int it = 0; it < 2; ++it) {
        int idx = it * 256 + tid;           // 0..511
        int node = idx >> 3, k8 = idx & 7;
        if (base + node < N_NODES) {
            half8v vv = *(const half8v*)&xs[node * 72 + k8 * 8];
            *(half8v*)&xw2h[(size_t)(base + node) * 64 + k8 * 8] = vv;
        }
    }
}

// ---- Layer 2 aggregation: 8 edges/iter, half8 gathers, fused u/v epilogue ----

__global__ __launch_bounds__(256) void agg2_kernel(
        const int* __restrict__ off, const int* __restrict__ csr_src,
        const float* __restrict__ as2, const float* __restrict__ ad2,
        const _Float16* __restrict__ xw2h, const float* __restrict__ b2,
        const float* __restrict__ lw, float* __restrict__ u, float* __restrict__ v) {
    int wv = threadIdx.x >> 6, lane = threadIdx.x & 63;
    int n = blockIdx.x * 4 + wv;
    if (n >= N_NODES) return;
    int s = off[n], e = off[n + 1];
    float adn = ad2[n];
    int e8 = lane >> 3, q = lane & 7;       // edge slot 0..7; cols 8q..8q+7
    float acc[8];
#pragma unroll
    for (int i = 0; i < 8; i++) acc[i] = 0.f;
    float sum = 0.f;
    for (int b = s; b < e; b += 64) {
        int cnt = min(64, e - b);
        int l = lane < cnt ? lane : cnt - 1;
        int srcv = csr_src[b + l];
        float a = as2[srcv];
        float ev = a + adn; ev = ev > 0.f ? ev : NEG_SLOPE * ev;
        float fv = (lane < cnt) ? __expf(ev) : 0.f;
        float r = fv;
#pragma unroll
        for (int m = 32; m >= 1; m >>= 1) r += __shfl_xor(r, m);
        sum += r;
        for (int jj = 0; jj < cnt; jj += 8) {
            int j = jj + e8;
            bool val = j < cnt;
            int sl = val ? j : jj;
            int src = __shfl(srcv, sl);
            float f = __shfl(fv, sl);
            if (!val) f = 0.f;
            half8v hv = *(const half8v*)&xw2h[(size_t)src * 64 + 8 * q];
#pragma unroll
            for (int i = 0; i < 8; i++) acc[i] = fmaf((float)hv[i], f, acc[i]);
        }
    }
#pragma unroll
    for (int m = 32; m >= 8; m >>= 1) {
#pragma unroll
        for (int i = 0; i < 8; i++) acc[i] += __shfl_xor(acc[i], m);
    }
    int c = 8 * q;
    float pu = 0.f, pv = 0.f;
#pragma unroll
    for (int i = 0; i < 8; i++) {
        float zi = acc[i] / sum + b2[c + i];
        pu = fmaf(zi, lw[c + i], pu);
        pv = fmaf(zi, lw[64 + c + i], pv);
    }
#pragma unroll
    for (int m = 4; m >= 1; m >>= 1) {
        pu += __shfl_xor(pu, m);
        pv += __shfl_xor(pv, m);
    }
    if (lane == 0) { u[n] = pu; v[n] = pv; }
}

// ---------------- Link decode: out = u[s] + v[d] + lb ----------------

__global__ __launch_bounds__(256) void decode_kernel(
        const int* __restrict__ pos_ei, const int* __restrict__ neg_ei,
        const float* __restrict__ u, const float* __restrict__ v,
        const float* __restrict__ lb, float* __restrict__ out) {
    int idx = blockIdx.x * 256 + threadIdx.x;
    if (idx >= 2 * P_CAND) return;
    const int* ei; int p;
    if (idx < P_CAND) { ei = pos_ei; p = idx; }
    else              { ei = neg_ei; p = idx - P_CAND; }
    int sN = ei[p], dN = ei[P_CAND + p];
    out[idx] = u[sN] + v[dN] + lb[0];
}

// ---------------- launch ----------------

extern "C" void kernel_launch(void* const* d_in, const int* in_sizes, int n_in,
                              void* d_out, int out_size, void* d_ws, size_t ws_size,
                              hipStream_t stream) {
    const float* x        = (const float*)d_in[0];
    const int*   ei       = (const int*)d_in[1];
    const int*   pos_ei   = (const int*)d_in[3];
    const int*   neg_ei   = (const int*)d_in[4];
    const float* W1       = (const float*)d_in[5];
    const float* att_src1 = (const float*)d_in[6];
    const float* att_dst1 = (const float*)d_in[7];
    const float* b1       = (const float*)d_in[8];
    const float* W2       = (const float*)d_in[9];
    const float* att_src2 = (const float*)d_in[10];
    const float* att_dst2 = (const float*)d_in[11];
    const float* b2       = (const float*)d_in[12];
    const float* lw       = (const float*)d_in[13];
    const float* lb       = (const float*)d_in[14];
    float* out = (float*)d_out;

    char* ws = (char*)d_ws;
    size_t o = 0;
    auto alloc = [&](size_t bytes) -> char* {
        char* p = ws + o;
        o += (bytes + 511) & ~(size_t)511;
        return p;
    };
    _Float16* xw1h  = (_Float16*)alloc((size_t)N_NODES * 128 * 2);  // reused: xw2h
    float*    h     = (float*)alloc((size_t)N_NODES * 128 * 4);
    float*    u     = (float*)alloc((size_t)N_NODES * 4);
    float*    v     = (float*)alloc((size_t)N_NODES * 4);
    float*    as1   = (float*)alloc((size_t)N_NODES * 2 * 4);
    float*    ad1   = (float*)alloc((size_t)N_NODES * 2 * 4);
    float*    as2   = (float*)alloc((size_t)N_NODES * 4);
    float*    ad2   = (float*)alloc((size_t)N_NODES * 4);
    int*      off   = (int*)alloc((size_t)(N_NODES + 1) * 4);
    int*      hist  = (int*)alloc((size_t)NTOT * 4);
    int*      histS = (int*)alloc((size_t)NTOT * 4);
    unsigned* binned= (unsigned*)alloc((size_t)EP * 4);
    int*      csr   = (int*)alloc((size_t)EP * 4);
    _Float16* W1T   = (_Float16*)alloc((size_t)128 * 128 * 2);
    _Float16* W2T   = (_Float16*)alloc((size_t)64 * 128 * 2);
    _Float16* xw2h  = xw1h;    // xw1h dead after agg1

    prep_kernel<<<96, 256, 0, stream>>>(W1, W2, W1T, W2T);
    hist_kernel<<<NB2, 256, 0, stream>>>(ei, hist);
    scan2_kernel<<<1, 1024, 0, stream>>>(hist, histS);
    scatterbin_kernel<<<NB2, 256, 0, stream>>>(ei, histS, binned);
    binsort_kernel<<<NBIN, 1024, 0, stream>>>(binned, histS, off, csr);
    gemm1_kernel<<<(N_NODES + 63) / 64, 256, 0, stream>>>(x, W1T, att_src1, att_dst1, xw1h, as1, ad1);
    agg1_kernel<<<(N_NODES + 3) / 4, 256, 0, stream>>>(off, csr, as1, ad1, xw1h, b1, h);
    gemm2_kernel<<<(N_NODES + 63) / 64, 256, 0, stream>>>(h, W2T, att_src2, att_dst2, xw2h, as2, ad2);
    agg2_kernel<<<(N_NODES + 3) / 4, 256, 0, stream>>>(off, csr, as2, ad2, xw2h, b2, lw, u, v);
    decode_kernel<<<(2 * P_CAND + 255) / 256, 256, 0, stream>>>(pos_ei, neg_ei, u, v, lb, out);
}